// Round 5
// baseline (348.829 us; speedup 1.0000x reference)
//
#include <hip/hip_runtime.h>
#include <math.h>

// Problem constants
#define B_  8
#define N_  196
#define C_  12
#define D_  768
#define H_  12
#define R_  (B_*N_*C_)      // 18816 rows
#define NQKV_PAD 768        // 720 real qkv cols padded to 768
#define KP  2304            // packed logical K (3 x 768: hi*hi, lo*hi, hi*lo)
#define KA  1536            // A-side storage K ([hi|lo]; third segment wraps to hi)

typedef __attribute__((ext_vector_type(8))) short bf16x8;   // 8 bf16 = 4 VGPR
typedef __attribute__((ext_vector_type(4))) float f32x4;

__device__ inline unsigned short f2bf(float f) {
    union { float f; unsigned u; } v; v.f = f;
    unsigned r = v.u + 0x7fffu + ((v.u >> 16) & 1u);   // RNE
    return (unsigned short)(r >> 16);
}
__device__ inline float bf2f(unsigned short h) {
    union { unsigned u; float f; } v; v.u = ((unsigned)h) << 16; return v.f;
}

// ---------------------------------------------------------------------------
// x (fp32, R x 768) -> packed A' (bf16, R x 1536 = [hi row | lo row])
// ---------------------------------------------------------------------------
__global__ __launch_bounds__(256) void convert_x_p(
    const float* __restrict__ in, unsigned short* __restrict__ Ap, int nrows)
{
    int i = (blockIdx.x * 256 + threadIdx.x) * 4;
    if (i >= nrows * 768) return;
    const int row = i / 768, col = i % 768;
    float4 v = *reinterpret_cast<const float4*>(in + i);
    ushort4 h, l;
    h.x = f2bf(v.x); l.x = f2bf(v.x - bf2f(h.x));
    h.y = f2bf(v.y); l.y = f2bf(v.y - bf2f(h.y));
    h.z = f2bf(v.z); l.z = f2bf(v.z - bf2f(h.z));
    h.w = f2bf(v.w); l.w = f2bf(v.w - bf2f(h.w));
    *reinterpret_cast<ushort4*>(Ap + (size_t)row * KA + col)       = h;
    *reinterpret_cast<ushort4*>(Ap + (size_t)row * KA + 768 + col) = l;
}

// w_qkv_c (144x768) + w_qkv_s (576x768) -> packed B' (768 x 2304 = [hi|hi|lo])
__global__ __launch_bounds__(256) void convert_wqkv_p(
    const float* __restrict__ wc, const float* __restrict__ ws,
    unsigned short* __restrict__ Bp)
{
    int i = (blockIdx.x * 256 + threadIdx.x) * 4;
    if (i >= 768 * 768) return;
    const int r = i / 768, k = i % 768;
    float4 v = make_float4(0.f, 0.f, 0.f, 0.f);
    if (r < 144)      v = *reinterpret_cast<const float4*>(wc + r * 768 + k);
    else if (r < 720) v = *reinterpret_cast<const float4*>(ws + (r - 144) * 768 + k);
    ushort4 h, l;
    h.x = f2bf(v.x); l.x = f2bf(v.x - bf2f(h.x));
    h.y = f2bf(v.y); l.y = f2bf(v.y - bf2f(h.y));
    h.z = f2bf(v.z); l.z = f2bf(v.z - bf2f(h.z));
    h.w = f2bf(v.w); l.w = f2bf(v.w - bf2f(h.w));
    unsigned short* base = Bp + (size_t)r * KP + k;
    *reinterpret_cast<ushort4*>(base)        = h;
    *reinterpret_cast<ushort4*>(base + 768)  = h;
    *reinterpret_cast<ushort4*>(base + 1536) = l;
}

// w_proj (768x768) -> packed B' (768 x 2304 = [hi|hi|lo])
__global__ __launch_bounds__(256) void convert_wp_p(
    const float* __restrict__ w, unsigned short* __restrict__ Bp)
{
    int i = (blockIdx.x * 256 + threadIdx.x) * 4;
    if (i >= 768 * 768) return;
    const int r = i / 768, k = i % 768;
    float4 v = *reinterpret_cast<const float4*>(w + i);
    ushort4 h, l;
    h.x = f2bf(v.x); l.x = f2bf(v.x - bf2f(h.x));
    h.y = f2bf(v.y); l.y = f2bf(v.y - bf2f(h.y));
    h.z = f2bf(v.z); l.z = f2bf(v.z - bf2f(h.z));
    h.w = f2bf(v.w); l.w = f2bf(v.w - bf2f(h.w));
    unsigned short* base = Bp + (size_t)r * KP + k;
    *reinterpret_cast<ushort4*>(base)        = h;
    *reinterpret_cast<ushort4*>(base + 768)  = h;
    *reinterpret_cast<ushort4*>(base + 1536) = l;
}

// ---------------------------------------------------------------------------
// Packed-K bf16 MFMA GEMM: out[M x Nt](fp32) = A'[M x KP(wrap KA)] @ B'^T.
// 128x128 tile, 4 waves x 64x64, BK=32, 2-phase double-buffer (32KB LDS),
// chunked-bijective XCD swizzle, nt-fast for A-panel L2 reuse.
// ---------------------------------------------------------------------------
#define BM 128
#define BN 128
#define BK 32

__device__ inline void gload16(const unsigned short* src, void* ldsbase) {
    __builtin_amdgcn_global_load_lds(
        (const __attribute__((address_space(1))) unsigned int*)src,
        (__attribute__((address_space(3))) unsigned int*)ldsbase, 16, 0, 0);
}

__global__ __launch_bounds__(256) void gemm_bf16p(
    const unsigned short* __restrict__ A, const unsigned short* __restrict__ Bm,
    const float* __restrict__ bias,
    float* __restrict__ outp, int M, int Nt, int ntiles)
{
    __shared__ unsigned short sA[2][BM][BK];
    __shared__ unsigned short sB[2][BN][BK];

    // chunked bijective XCD swizzle (m204)
    const int nwg = gridDim.x;
    const int bid = blockIdx.x;
    const int xcd = bid & 7, slot = bid >> 3;
    const int q = nwg >> 3, r = nwg & 7;
    const int wg = (xcd < r ? xcd * (q + 1) : r * (q + 1) + (xcd - r) * q) + slot;
    const int mt = wg / ntiles, nt = wg - mt * ntiles;   // nt fast: A-panel reuse
    const int m0 = mt * BM, n0 = nt * BN;

    const int tid = threadIdx.x;
    const int w = tid >> 6, l = tid & 63;
    const int wr = (w >> 1) * 64, wc = (w & 1) * 64;

    f32x4 acc[4][4];
    #pragma unroll
    for (int i = 0; i < 4; ++i)
        #pragma unroll
        for (int j = 0; j < 4; ++j)
            acc[i][j] = (f32x4){0.f, 0.f, 0.f, 0.f};

    // staging: 8KB tile per array; wave w covers [w*1024,+1024) and
    // [4096+w*1024,+1024); lane adds l*16.  row = o>>6, col = (o&63)>>1.
    const int seg0 = w * 1024, seg1 = 4096 + w * 1024;
    const int o0 = seg0 + l * 16, o1 = seg1 + l * 16;
    const int r0 = o0 >> 6, c0 = (o0 & 63) >> 1;
    const int r1 = o1 >> 6, c1 = (o1 & 63) >> 1;

    const int lr = l & 15;
    const int kb = (l >> 4) * 8;

#define STAGE(buf, kk) {                                                         \
    const int ka = (kk) >= KA ? (kk) - KA : (kk);  /* A wrap: 3rd seg = hi */    \
    gload16(A  + (size_t)(m0 + r0) * KA + ka   + c0, (char*)sA[buf] + seg0);     \
    gload16(A  + (size_t)(m0 + r1) * KA + ka   + c1, (char*)sA[buf] + seg1);     \
    gload16(Bm + (size_t)(n0 + r0) * KP + (kk) + c0, (char*)sB[buf] + seg0);     \
    gload16(Bm + (size_t)(n0 + r1) * KP + (kk) + c1, (char*)sB[buf] + seg1); }

    STAGE(0, 0);
    __syncthreads();

    const int KT = KP / BK;   // 72
    int cur = 0;
    for (int t = 0; t < KT; ++t) {
        if (t + 1 < KT) { STAGE(cur ^ 1, (t + 1) * BK); }   // loads fly over MFMAs

        bf16x8 ah[4];
        #pragma unroll
        for (int fm = 0; fm < 4; ++fm)
            ah[fm] = *reinterpret_cast<const bf16x8*>(&sA[cur][wr + fm * 16 + lr][kb]);
        #pragma unroll
        for (int fn = 0; fn < 4; ++fn) {
            const bf16x8 bh = *reinterpret_cast<const bf16x8*>(&sB[cur][wc + fn * 16 + lr][kb]);
            #pragma unroll
            for (int fm = 0; fm < 4; ++fm)
                acc[fm][fn] = __builtin_amdgcn_mfma_f32_16x16x32_bf16(ah[fm], bh, acc[fm][fn], 0, 0, 0);
        }
        __syncthreads();   // drains vmcnt(0): next buffer ready
        cur ^= 1;
    }
#undef STAGE

    const int rg = (l >> 4) * 4;
    #pragma unroll
    for (int fm = 0; fm < 4; ++fm) {
        #pragma unroll
        for (int fn = 0; fn < 4; ++fn) {
            const int row = m0 + wr + fm * 16 + rg;
            const int col = n0 + wc + fn * 16 + lr;
            const float bv = bias ? bias[col] : 0.f;
            #pragma unroll
            for (int rr = 0; rr < 4; ++rr)
                outp[(size_t)(row + rr) * Nt + col] = acc[fm][fn][rr] + bv;
        }
    }
}

// ---------------------------------------------------------------------------
// MFMA spatial attention (unchanged, verified).
// ---------------------------------------------------------------------------
__global__ __launch_bounds__(256) void spatial_attn_mfma(
    const float* __restrict__ qkv,
    float* __restrict__ xs_out)
{
    __shared__ unsigned short Kl[224][32];
    __shared__ unsigned short Ql[208][40];
    __shared__ unsigned short VtH[16][224];
    __shared__ unsigned short VtL[16][224];
    __shared__ unsigned short Pb[4][16][72];

    const int bid = blockIdx.x;                // 1152 = 8*12*12
    const int c = bid % 12;
    const int h = (bid / 12) % 12;
    const int b = bid / 144;
    const int tid = threadIdx.x;
    const int w = tid >> 6, l = tid & 63;
    const int fl = l & 15, g = l >> 4;

    for (int idx = tid; idx < N_ * 16; idx += 256) {
        const int n = idx >> 4, e = idx & 15;
        const float* base = qkv + (size_t)((b * N_ + n) * 12 + c) * NQKV_PAD + 144 + h * 16 + e;
        const float qv = base[0] * 0.25f;
        const float kv = base[192];
        const float vv = base[384];
        const unsigned short qh = f2bf(qv), kh = f2bf(kv), vh = f2bf(vv);
        Ql[n][e]      = qh;  Ql[n][16 + e] = f2bf(qv - bf2f(qh));
        Kl[n][e]      = kh;  Kl[n][16 + e] = f2bf(kv - bf2f(kh));
        VtH[e][n]     = vh;  VtL[e][n]     = f2bf(vv - bf2f(vh));
    }
    for (int idx = tid; idx < 16 * 28; idx += 256) {
        const int d = idx / 28, n = 196 + idx % 28;
        VtH[d][n] = 0; VtL[d][n] = 0;
    }
    __syncthreads();

    f32x4 accO[4];
    float mrun[4], lsum[4];
    #pragma unroll
    for (int j = 0; j < 4; ++j) {
        accO[j] = (f32x4){0.f, 0.f, 0.f, 0.f};
        mrun[j] = -INFINITY; lsum[j] = 0.f;
    }
    const f32x4 zf = (f32x4){0.f, 0.f, 0.f, 0.f};
    const bf16x8 zb = (bf16x8){0, 0, 0, 0, 0, 0, 0, 0};

    for (int ch = 0; ch < 7; ++ch) {
        const int kb0 = ch * 32;
        const bf16x8 A1a = *reinterpret_cast<const bf16x8*>(&Kl[kb0 + fl][8 * g]);
        const bf16x8 A1b = *reinterpret_cast<const bf16x8*>(&Kl[kb0 + 16 + fl][8 * g]);
        const bf16x8 A2a = *reinterpret_cast<const bf16x8*>(&Kl[kb0 + fl][8 * (g & 1)]);
        const bf16x8 A2b = *reinterpret_cast<const bf16x8*>(&Kl[kb0 + 16 + fl][8 * (g & 1)]);
        const bf16x8 AvH = *reinterpret_cast<const bf16x8*>(&VtH[fl][kb0 + 8 * g]);
        const bf16x8 AvL = *reinterpret_cast<const bf16x8*>(&VtL[fl][kb0 + 8 * g]);

        #pragma unroll
        for (int j = 0; j < 4; ++j) {
            const int qt = w + 4 * j;
            if (qt > 12) continue;
            const int qrow = qt * 16 + fl;
            const bf16x8 Bq1 = *reinterpret_cast<const bf16x8*>(&Ql[qrow][8 * (g & 1)]);
            bf16x8 Bq2 = *reinterpret_cast<const bf16x8*>(&Ql[qrow][16 + 8 * (g & 1)]);
            if (g >= 2) Bq2 = zb;

            f32x4 T0 = zf, T1 = zf;
            T0 = __builtin_amdgcn_mfma_f32_16x16x32_bf16(A1a, Bq1, T0, 0, 0, 0);
            T0 = __builtin_amdgcn_mfma_f32_16x16x32_bf16(A2a, Bq2, T0, 0, 0, 0);
            T1 = __builtin_amdgcn_mfma_f32_16x16x32_bf16(A1b, Bq1, T1, 0, 0, 0);
            T1 = __builtin_amdgcn_mfma_f32_16x16x32_bf16(A2b, Bq2, T1, 0, 0, 0);

            float s0 = T0[0], s1 = T0[1], s2 = T0[2], s3 = T0[3];
            float s4 = T1[0], s5 = T1[1], s6 = T1[2], s7 = T1[3];
            if (ch == 6) {
                const int kg = kb0 + 4 * g;
                if (kg + 0 >= 196) s0 = -1e30f;
                if (kg + 1 >= 196) s1 = -1e30f;
                if (kg + 2 >= 196) s2 = -1e30f;
                if (kg + 3 >= 196) s3 = -1e30f;
                s4 = -1e30f; s5 = -1e30f; s6 = -1e30f; s7 = -1e30f;
            }
            float cm = fmaxf(fmaxf(fmaxf(s0, s1), fmaxf(s2, s3)),
                             fmaxf(fmaxf(s4, s5), fmaxf(s6, s7)));
            cm = fmaxf(cm, __shfl_xor(cm, 16));
            cm = fmaxf(cm, __shfl_xor(cm, 32));
            const float mn = fmaxf(mrun[j], cm);
            const float corr = __expf(mrun[j] - mn);
            mrun[j] = mn;
            const float p0 = __expf(s0 - mn), p1 = __expf(s1 - mn);
            const float p2 = __expf(s2 - mn), p3 = __expf(s3 - mn);
            const float p4 = __expf(s4 - mn), p5 = __expf(s5 - mn);
            const float p6 = __expf(s6 - mn), p7 = __expf(s7 - mn);
            float ps = ((p0 + p1) + (p2 + p3)) + ((p4 + p5) + (p6 + p7));
            ps += __shfl_xor(ps, 16);
            ps += __shfl_xor(ps, 32);
            lsum[j] = lsum[j] * corr + ps;
            accO[j][0] *= corr; accO[j][1] *= corr;
            accO[j][2] *= corr; accO[j][3] *= corr;

            unsigned short h0 = f2bf(p0), h1 = f2bf(p1), h2 = f2bf(p2), h3 = f2bf(p3);
            unsigned short h4 = f2bf(p4), h5 = f2bf(p5), h6 = f2bf(p6), h7 = f2bf(p7);
            uint2 whi0, whi1, wlo0, wlo1;
            whi0.x = (unsigned)h0 | ((unsigned)h1 << 16);
            whi0.y = (unsigned)h2 | ((unsigned)h3 << 16);
            whi1.x = (unsigned)h4 | ((unsigned)h5 << 16);
            whi1.y = (unsigned)h6 | ((unsigned)h7 << 16);
            wlo0.x = (unsigned)f2bf(p0 - bf2f(h0)) | ((unsigned)f2bf(p1 - bf2f(h1)) << 16);
            wlo0.y = (unsigned)f2bf(p2 - bf2f(h2)) | ((unsigned)f2bf(p3 - bf2f(h3)) << 16);
            wlo1.x = (unsigned)f2bf(p4 - bf2f(h4)) | ((unsigned)f2bf(p5 - bf2f(h5)) << 16);
            wlo1.y = (unsigned)f2bf(p6 - bf2f(h6)) | ((unsigned)f2bf(p7 - bf2f(h7)) << 16);
            *reinterpret_cast<uint2*>(&Pb[w][fl][4 * g])      = whi0;
            *reinterpret_cast<uint2*>(&Pb[w][fl][16 + 4 * g]) = whi1;
            *reinterpret_cast<uint2*>(&Pb[w][fl][32 + 4 * g]) = wlo0;
            *reinterpret_cast<uint2*>(&Pb[w][fl][48 + 4 * g]) = wlo1;

            const bf16x8 BpH = *reinterpret_cast<const bf16x8*>(&Pb[w][fl][8 * g]);
            const bf16x8 BpL = *reinterpret_cast<const bf16x8*>(&Pb[w][fl][32 + 8 * g]);
            accO[j] = __builtin_amdgcn_mfma_f32_16x16x32_bf16(AvH, BpH, accO[j], 0, 0, 0);
            accO[j] = __builtin_amdgcn_mfma_f32_16x16x32_bf16(AvL, BpH, accO[j], 0, 0, 0);
            accO[j] = __builtin_amdgcn_mfma_f32_16x16x32_bf16(AvH, BpL, accO[j], 0, 0, 0);
        }
    }

    #pragma unroll
    for (int j = 0; j < 4; ++j) {
        const int qt = w + 4 * j;
        if (qt > 12) continue;
        const int n = qt * 16 + fl;
        if (n < 196) {
            const float inv = 1.f / lsum[j];
            float4 o;
            o.x = accO[j][0] * inv; o.y = accO[j][1] * inv;
            o.z = accO[j][2] * inv; o.w = accO[j][3] * inv;
            const size_t base = ((size_t)((b * 12 + h) * N_ + n) * 12 + c) * 16 + 4 * g;
            *reinterpret_cast<float4*>(&xs_out[base]) = o;
        }
    }
}

// ---------------------------------------------------------------------------
// Channel attention (12x4 per (b,h,n)) + outer-product combine -> y' packed
// (bf16 [hi row | lo row], stride KA)
// ---------------------------------------------------------------------------
__global__ __launch_bounds__(64) void chan_attn_combine(
    const float* __restrict__ qkv,
    const float* __restrict__ xs,
    unsigned short* __restrict__ Yp)
{
    const int bid = blockIdx.x;
    const int n = bid % N_;
    const int h = (bid / N_) % 12;
    const int b = bid / (N_ * 12);
    const int t = threadIdx.x;

    __shared__ float sQ[12][4], sK[12][4], sV[12][4], sXc[12][4];
    __shared__ float sXs[12][16];

    for (int idx = t; idx < 144; idx += 64) {
        const int c = idx / 12, rem = idx % 12, s = rem >> 2, e = rem & 3;
        const float v = qkv[(size_t)((b * N_ + n) * 12 + c) * NQKV_PAD + s * 48 + h * 4 + e];
        if (s == 0) sQ[c][e] = v;
        else if (s == 1) sK[c][e] = v;
        else sV[c][e] = v;
    }
    for (int idx = t; idx < 192; idx += 64) {
        const int c = idx >> 4, j = idx & 15;
        sXs[c][j] = xs[(size_t)(((b * 12 + h) * N_ + n) * 12 + c) * 16 + j];
    }
    __syncthreads();

    if (t < 12) {
        const int c = t;
        float s[12];
        float m = -INFINITY;
        #pragma unroll
        for (int c2 = 0; c2 < 12; ++c2) {
            float d = 0.f;
            #pragma unroll
            for (int e = 0; e < 4; ++e) d += sQ[c][e] * sK[c2][e];
            s[c2] = d * 0.5f;
            m = fmaxf(m, s[c2]);
        }
        float lsum = 0.f;
        #pragma unroll
        for (int c2 = 0; c2 < 12; ++c2) { s[c2] = __expf(s[c2] - m); lsum += s[c2]; }
        const float inv = 1.f / lsum;
        #pragma unroll
        for (int i = 0; i < 4; ++i) {
            float a = 0.f;
            #pragma unroll
            for (int c2 = 0; c2 < 12; ++c2) a += s[c2] * sV[c2][i];
            sXc[c][i] = a * inv;
        }
    }
    __syncthreads();

    const size_t ybase = ((size_t)(b * N_ + n) * 12 + h) * (size_t)KA;
    #pragma unroll
    for (int k = 0; k < 12; ++k) {
        const float v = sXc[k][t >> 4] * sXs[k][t & 15];
        const unsigned short hv = f2bf(v);
        Yp[ybase + k * 64 + t]       = hv;
        Yp[ybase + 768 + k * 64 + t] = f2bf(v - bf2f(hv));
    }
}

// ---------------------------------------------------------------------------
extern "C" void kernel_launch(void* const* d_in, const int* in_sizes, int n_in,
                              void* d_out, int out_size, void* d_ws, size_t ws_size,
                              hipStream_t stream) {
    const float* x       = (const float*)d_in[0];
    const float* w_qkv_c = (const float*)d_in[1];
    const float* w_qkv_s = (const float*)d_in[2];
    const float* w_proj  = (const float*)d_in[3];
    const float* b_proj  = (const float*)d_in[4];
    float* out = (float*)d_out;

    // Workspace (~137 MB):
    //   Ap  : R x 1536 bf16 (x packed; aliased as y packed after qkv GEMM)
    //   wqkv_p, wp_p : 768 x 2304 bf16
    //   qkv fp32 : R x 768 ; xs fp32 : B*H*N*C x 16
    unsigned short* Ap     = (unsigned short*)d_ws;
    unsigned short* wqkv_p = Ap + (size_t)R_ * KA;
    unsigned short* wp_p   = wqkv_p + (size_t)768 * KP;
    float* qkv = (float*)(wp_p + (size_t)768 * KP);
    float* xs  = qkv + (size_t)R_ * NQKV_PAD;
    unsigned short* Yp = Ap;   // alias: x packed dead after qkv GEMM

    convert_x_p<<<(R_ * 768) / 1024, 256, 0, stream>>>(x, Ap, R_);
    convert_wqkv_p<<<(768 * 768) / 1024, 256, 0, stream>>>(w_qkv_c, w_qkv_s, wqkv_p);
    convert_wp_p<<<(768 * 768) / 1024, 256, 0, stream>>>(w_proj, wp_p);

    {
        const int mtiles = R_ / BM, ntiles = NQKV_PAD / BN;
        gemm_bf16p<<<mtiles * ntiles, 256, 0, stream>>>(
            Ap, wqkv_p, nullptr, qkv, R_, NQKV_PAD, ntiles);
    }
    spatial_attn_mfma<<<B_ * H_ * C_, 256, 0, stream>>>(qkv, xs);
    chan_attn_combine<<<B_ * H_ * N_, 64, 0, stream>>>(qkv, xs, Yp);
    {
        const int mtiles = R_ / BM, ntiles = D_ / BN;
        gemm_bf16p<<<mtiles * ntiles, 256, 0, stream>>>(
            Yp, wp_p, b_proj, out, R_, D_, ntiles);
    }
}

// Round 6
// 282.595 us; speedup vs baseline: 1.2344x; 1.2344x over previous
//
#include <hip/hip_runtime.h>
#include <math.h>

// Problem constants
#define B_  8
#define N_  196
#define C_  12
#define D_  768
#define H_  12
#define R_  (B_*N_*C_)      // 18816 rows
#define MPAD 18944          // 74 * 256
#define NQKV_PAD 768
#define KP  2304            // packed logical K (3 x 768: hi*hi, lo*hi, hi*lo)
#define KA  1536            // A-side storage ([hi|lo]; third segment wraps to hi)

typedef __attribute__((ext_vector_type(8))) short bf16x8;
typedef __attribute__((ext_vector_type(4))) float f32x4;

__device__ inline unsigned short f2bf(float f) {
    union { float f; unsigned u; } v; v.f = f;
    unsigned r = v.u + 0x7fffu + ((v.u >> 16) & 1u);   // RNE
    return (unsigned short)(r >> 16);
}
__device__ inline float bf2f(unsigned short h) {
    union { unsigned u; float f; } v; v.u = ((unsigned)h) << 16; return v.f;
}

__device__ inline void gload16(const unsigned short* src, void* ldsbase) {
    __builtin_amdgcn_global_load_lds(
        (const __attribute__((address_space(1))) unsigned int*)src,
        (__attribute__((address_space(3))) unsigned int*)ldsbase, 16, 0, 0);
}

// ---------------------------------------------------------------------------
// x (fp32, R x 768) -> packed A' (bf16, rows x 1536 = [hi | lo])
// ---------------------------------------------------------------------------
__global__ __launch_bounds__(256) void convert_x_p(
    const float* __restrict__ in, unsigned short* __restrict__ Ap, int nrows)
{
    int i = (blockIdx.x * 256 + threadIdx.x) * 4;
    if (i >= nrows * 768) return;
    const int row = i / 768, col = i % 768;
    float4 v = *reinterpret_cast<const float4*>(in + i);
    ushort4 h, l;
    h.x = f2bf(v.x); l.x = f2bf(v.x - bf2f(h.x));
    h.y = f2bf(v.y); l.y = f2bf(v.y - bf2f(h.y));
    h.z = f2bf(v.z); l.z = f2bf(v.z - bf2f(h.z));
    h.w = f2bf(v.w); l.w = f2bf(v.w - bf2f(h.w));
    *reinterpret_cast<ushort4*>(Ap + (size_t)row * KA + col)       = h;
    *reinterpret_cast<ushort4*>(Ap + (size_t)row * KA + 768 + col) = l;
}

// w_qkv_c (144x768) + w_qkv_s (576x768) -> packed B' (768 x 2304 = [hi|hi|lo])
__global__ __launch_bounds__(256) void convert_wqkv_p(
    const float* __restrict__ wc, const float* __restrict__ ws,
    unsigned short* __restrict__ Bp)
{
    int i = (blockIdx.x * 256 + threadIdx.x) * 4;
    if (i >= 768 * 768) return;
    const int r = i / 768, k = i % 768;
    float4 v = make_float4(0.f, 0.f, 0.f, 0.f);
    if (r < 144)      v = *reinterpret_cast<const float4*>(wc + r * 768 + k);
    else if (r < 720) v = *reinterpret_cast<const float4*>(ws + (r - 144) * 768 + k);
    ushort4 h, l;
    h.x = f2bf(v.x); l.x = f2bf(v.x - bf2f(h.x));
    h.y = f2bf(v.y); l.y = f2bf(v.y - bf2f(h.y));
    h.z = f2bf(v.z); l.z = f2bf(v.z - bf2f(h.z));
    h.w = f2bf(v.w); l.w = f2bf(v.w - bf2f(h.w));
    unsigned short* base = Bp + (size_t)r * KP + k;
    *reinterpret_cast<ushort4*>(base)        = h;
    *reinterpret_cast<ushort4*>(base + 768)  = h;
    *reinterpret_cast<ushort4*>(base + 1536) = l;
}

__global__ __launch_bounds__(256) void convert_wp_p(
    const float* __restrict__ w, unsigned short* __restrict__ Bp)
{
    int i = (blockIdx.x * 256 + threadIdx.x) * 4;
    if (i >= 768 * 768) return;
    const int r = i / 768, k = i % 768;
    float4 v = *reinterpret_cast<const float4*>(w + i);
    ushort4 h, l;
    h.x = f2bf(v.x); l.x = f2bf(v.x - bf2f(h.x));
    h.y = f2bf(v.y); l.y = f2bf(v.y - bf2f(h.y));
    h.z = f2bf(v.z); l.z = f2bf(v.z - bf2f(h.z));
    h.w = f2bf(v.w); l.w = f2bf(v.w - bf2f(h.w));
    unsigned short* base = Bp + (size_t)r * KP + k;
    *reinterpret_cast<ushort4*>(base)        = h;
    *reinterpret_cast<ushort4*>(base + 768)  = h;
    *reinterpret_cast<ushort4*>(base + 1536) = l;
}

// ---------------------------------------------------------------------------
// 256x256 8-phase bf16 GEMM over packed K'=2304 (A wraps at 1536).
// 512 threads = 8 waves (2M x 4N), per-wave 128x64 output.
// K-unit = 32 (one 16x16x32 k-step); 4 rotating 16KB LDS slots per operand.
// Per phase: {ds_read 8|4 b128, stage 1 slot (2 gload_lds), barrier,
//             setprio(1) 16 MFMA setprio(0), [vmcnt(8) at unit end], barrier}.
// Stages issued 3 units ahead; vmcnt gate = 4 issues x 2 gloads = 8 (never 0).
// LDS chunk swizzle: chunk' = chunk ^ ((row>>2)&3), applied on pre-swizzled
// global SOURCE (write side) and on the ds_read address (read side).
// ---------------------------------------------------------------------------
#define NU 72    // k-units (KP/32)

__global__ __launch_bounds__(512, 2) void gemm256_8ph(
    const unsigned short* __restrict__ A, const unsigned short* __restrict__ Bm,
    const float* __restrict__ bias,
    float* __restrict__ outp, int Mreal, int Nt, int ntiles)
{
    __shared__ unsigned short sA[4][256][32];   // 64 KB
    __shared__ unsigned short sB[4][256][32];   // 64 KB

    // chunked bijective XCD swizzle (m204), nt-fast for A-panel L2 reuse
    const int nwg = gridDim.x;
    const int bid = blockIdx.x;
    const int xcd = bid & 7, slot0 = bid >> 3;
    const int qq = nwg >> 3, rr8 = nwg & 7;
    const int wg = (xcd < rr8 ? xcd * (qq + 1) : rr8 * (qq + 1) + (xcd - rr8) * qq) + slot0;
    const int mt = wg / ntiles, ntl = wg - mt * ntiles;
    const int m0 = mt * 256, n0 = ntl * 256;

    const int tid = threadIdx.x;
    const int w = tid >> 6, l = tid & 63;
    const int fl = l & 15, g = l >> 4;
    const int wr = (w >> 2) * 128;          // wave row base (0 or 128)
    const int wc = (w & 3) * 64;            // wave col base
    const int rdk = ((g ^ ((fl >> 2) & 3)) & 3) * 8;   // swizzled read chunk

    // staging lane geometry: inst i covers LDS rows w*32+i*16 + (l>>2), chunk l&3
    const int lrow0 = w * 32 + (l >> 2);
    const int cp = (l & 3) ^ g;             // pre-swizzled source chunk (both insts)

    f32x4 acc[8][4];
    #pragma unroll
    for (int i = 0; i < 8; ++i)
        #pragma unroll
        for (int j = 0; j < 4; ++j)
            acc[i][j] = (f32x4){0.f, 0.f, 0.f, 0.f};

#define STAGE_A(u_, s_) {                                                        \
    const int kb = (u_) < 48 ? (u_) * 32 : (u_) * 32 - 1536;                     \
    const unsigned short* sp = A + (size_t)(m0 + lrow0) * KA + kb + cp * 8;      \
    gload16(sp,            (char*)&sA[s_][0][0] + w * 2048);                     \
    gload16(sp + 16 * KA,  (char*)&sA[s_][0][0] + w * 2048 + 1024); }

#define STAGE_B(u_, s_) {                                                        \
    const int kb = (u_) * 32;                                                    \
    const unsigned short* sp = Bm + (size_t)(n0 + lrow0) * KP + kb + cp * 8;     \
    gload16(sp,            (char*)&sB[s_][0][0] + w * 2048);                     \
    gload16(sp + 16 * KP,  (char*)&sB[s_][0][0] + w * 2048 + 1024); }

    // prologue: stage units 0..2 (A,B each); gate first unit; align
    STAGE_A(0, 0); STAGE_B(0, 0);
    STAGE_A(1, 1); STAGE_B(1, 1);
    STAGE_A(2, 2); STAGE_B(2, 2);
    asm volatile("s_waitcnt vmcnt(8)" ::: "memory");
    asm volatile("s_barrier" ::: "memory");

    for (int ut = 0; ut < NU; ut += 4) {
        #pragma unroll
        for (int du = 0; du < 4; ++du) {
            const int u = ut + du;
            const int s = du;                // u & 3
            const int sn = (du + 3) & 3;     // slot for unit u+3
            const bool dostage = (u + 3 < NU);

            // ---- even phase: rowfrags 0-3 x all colfrags ----
            bf16x8 afr[4], bfr[4];
            #pragma unroll
            for (int fm = 0; fm < 4; ++fm)
                afr[fm] = *reinterpret_cast<const bf16x8*>(&sA[s][wr + fm * 16 + fl][rdk]);
            #pragma unroll
            for (int fn = 0; fn < 4; ++fn)
                bfr[fn] = *reinterpret_cast<const bf16x8*>(&sB[s][wc + fn * 16 + fl][rdk]);
            if (dostage) STAGE_A(u + 3, sn);
            asm volatile("s_barrier" ::: "memory");
            __builtin_amdgcn_s_setprio(1);
            #pragma unroll
            for (int fn = 0; fn < 4; ++fn)
                #pragma unroll
                for (int fm = 0; fm < 4; ++fm)
                    acc[fm][fn] = __builtin_amdgcn_mfma_f32_16x16x32_bf16(
                        afr[fm], bfr[fn], acc[fm][fn], 0, 0, 0);
            __builtin_amdgcn_s_setprio(0);
            asm volatile("s_barrier" ::: "memory");

            // ---- odd phase: rowfrags 4-7 (B reused in regs) ----
            #pragma unroll
            for (int fm = 0; fm < 4; ++fm)
                afr[fm] = *reinterpret_cast<const bf16x8*>(&sA[s][wr + 64 + fm * 16 + fl][rdk]);
            if (dostage) STAGE_B(u + 3, sn);
            asm volatile("s_barrier" ::: "memory");
            __builtin_amdgcn_s_setprio(1);
            #pragma unroll
            for (int fn = 0; fn < 4; ++fn)
                #pragma unroll
                for (int fm = 0; fm < 4; ++fm)
                    acc[4 + fm][fn] = __builtin_amdgcn_mfma_f32_16x16x32_bf16(
                        afr[fm], bfr[fn], acc[4 + fm][fn], 0, 0, 0);
            __builtin_amdgcn_s_setprio(0);
            asm volatile("s_waitcnt vmcnt(8)" ::: "memory");   // gate unit u+1 (counted, never 0)
            asm volatile("s_barrier" ::: "memory");
        }
    }
#undef STAGE_A
#undef STAGE_B

    // epilogue: C/D layout col=lane&15, row=(lane>>4)*4+reg (m89-verified)
    const int rg = g * 4;
    #pragma unroll
    for (int fm = 0; fm < 8; ++fm) {
        #pragma unroll
        for (int fn = 0; fn < 4; ++fn) {
            const int row = m0 + wr + fm * 16 + rg;
            const int col = n0 + wc + fn * 16 + fl;
            const float bv = bias ? bias[col] : 0.f;
            #pragma unroll
            for (int r2 = 0; r2 < 4; ++r2)
                if (row + r2 < Mreal)
                    outp[(size_t)(row + r2) * Nt + col] = acc[fm][fn][r2] + bv;
        }
    }
}

// ---------------------------------------------------------------------------
// MFMA spatial attention (unchanged, verified).
// ---------------------------------------------------------------------------
__global__ __launch_bounds__(256) void spatial_attn_mfma(
    const float* __restrict__ qkv,
    float* __restrict__ xs_out)
{
    __shared__ unsigned short Kl[224][32];
    __shared__ unsigned short Ql[208][40];
    __shared__ unsigned short VtH[16][224];
    __shared__ unsigned short VtL[16][224];
    __shared__ unsigned short Pb[4][16][72];

    const int bid = blockIdx.x;                // 1152 = 8*12*12
    const int c = bid % 12;
    const int h = (bid / 12) % 12;
    const int b = bid / 144;
    const int tid = threadIdx.x;
    const int w = tid >> 6, l = tid & 63;
    const int fl = l & 15, g = l >> 4;

    for (int idx = tid; idx < N_ * 16; idx += 256) {
        const int n = idx >> 4, e = idx & 15;
        const float* base = qkv + (size_t)((b * N_ + n) * 12 + c) * NQKV_PAD + 144 + h * 16 + e;
        const float qv = base[0] * 0.25f;
        const float kv = base[192];
        const float vv = base[384];
        const unsigned short qh = f2bf(qv), kh = f2bf(kv), vh = f2bf(vv);
        Ql[n][e]      = qh;  Ql[n][16 + e] = f2bf(qv - bf2f(qh));
        Kl[n][e]      = kh;  Kl[n][16 + e] = f2bf(kv - bf2f(kh));
        VtH[e][n]     = vh;  VtL[e][n]     = f2bf(vv - bf2f(vh));
    }
    for (int idx = tid; idx < 16 * 28; idx += 256) {
        const int d = idx / 28, n = 196 + idx % 28;
        VtH[d][n] = 0; VtL[d][n] = 0;
    }
    __syncthreads();

    f32x4 accO[4];
    float mrun[4], lsum[4];
    #pragma unroll
    for (int j = 0; j < 4; ++j) {
        accO[j] = (f32x4){0.f, 0.f, 0.f, 0.f};
        mrun[j] = -INFINITY; lsum[j] = 0.f;
    }
    const f32x4 zf = (f32x4){0.f, 0.f, 0.f, 0.f};
    const bf16x8 zb = (bf16x8){0, 0, 0, 0, 0, 0, 0, 0};

    for (int ch = 0; ch < 7; ++ch) {
        const int kb0 = ch * 32;
        const bf16x8 A1a = *reinterpret_cast<const bf16x8*>(&Kl[kb0 + fl][8 * g]);
        const bf16x8 A1b = *reinterpret_cast<const bf16x8*>(&Kl[kb0 + 16 + fl][8 * g]);
        const bf16x8 A2a = *reinterpret_cast<const bf16x8*>(&Kl[kb0 + fl][8 * (g & 1)]);
        const bf16x8 A2b = *reinterpret_cast<const bf16x8*>(&Kl[kb0 + 16 + fl][8 * (g & 1)]);
        const bf16x8 AvH = *reinterpret_cast<const bf16x8*>(&VtH[fl][kb0 + 8 * g]);
        const bf16x8 AvL = *reinterpret_cast<const bf16x8*>(&VtL[fl][kb0 + 8 * g]);

        #pragma unroll
        for (int j = 0; j < 4; ++j) {
            const int qt = w + 4 * j;
            if (qt > 12) continue;
            const int qrow = qt * 16 + fl;
            const bf16x8 Bq1 = *reinterpret_cast<const bf16x8*>(&Ql[qrow][8 * (g & 1)]);
            bf16x8 Bq2 = *reinterpret_cast<const bf16x8*>(&Ql[qrow][16 + 8 * (g & 1)]);
            if (g >= 2) Bq2 = zb;

            f32x4 T0 = zf, T1 = zf;
            T0 = __builtin_amdgcn_mfma_f32_16x16x32_bf16(A1a, Bq1, T0, 0, 0, 0);
            T0 = __builtin_amdgcn_mfma_f32_16x16x32_bf16(A2a, Bq2, T0, 0, 0, 0);
            T1 = __builtin_amdgcn_mfma_f32_16x16x32_bf16(A1b, Bq1, T1, 0, 0, 0);
            T1 = __builtin_amdgcn_mfma_f32_16x16x32_bf16(A2b, Bq2, T1, 0, 0, 0);

            float s0 = T0[0], s1 = T0[1], s2 = T0[2], s3 = T0[3];
            float s4 = T1[0], s5 = T1[1], s6 = T1[2], s7 = T1[3];
            if (ch == 6) {
                const int kg = kb0 + 4 * g;
                if (kg + 0 >= 196) s0 = -1e30f;
                if (kg + 1 >= 196) s1 = -1e30f;
                if (kg + 2 >= 196) s2 = -1e30f;
                if (kg + 3 >= 196) s3 = -1e30f;
                s4 = -1e30f; s5 = -1e30f; s6 = -1e30f; s7 = -1e30f;
            }
            float cm = fmaxf(fmaxf(fmaxf(s0, s1), fmaxf(s2, s3)),
                             fmaxf(fmaxf(s4, s5), fmaxf(s6, s7)));
            cm = fmaxf(cm, __shfl_xor(cm, 16));
            cm = fmaxf(cm, __shfl_xor(cm, 32));
            const float mn = fmaxf(mrun[j], cm);
            const float corr = __expf(mrun[j] - mn);
            mrun[j] = mn;
            const float p0 = __expf(s0 - mn), p1 = __expf(s1 - mn);
            const float p2 = __expf(s2 - mn), p3 = __expf(s3 - mn);
            const float p4 = __expf(s4 - mn), p5 = __expf(s5 - mn);
            const float p6 = __expf(s6 - mn), p7 = __expf(s7 - mn);
            float ps = ((p0 + p1) + (p2 + p3)) + ((p4 + p5) + (p6 + p7));
            ps += __shfl_xor(ps, 16);
            ps += __shfl_xor(ps, 32);
            lsum[j] = lsum[j] * corr + ps;
            accO[j][0] *= corr; accO[j][1] *= corr;
            accO[j][2] *= corr; accO[j][3] *= corr;

            unsigned short h0 = f2bf(p0), h1 = f2bf(p1), h2 = f2bf(p2), h3 = f2bf(p3);
            unsigned short h4 = f2bf(p4), h5 = f2bf(p5), h6 = f2bf(p6), h7 = f2bf(p7);
            uint2 whi0, whi1, wlo0, wlo1;
            whi0.x = (unsigned)h0 | ((unsigned)h1 << 16);
            whi0.y = (unsigned)h2 | ((unsigned)h3 << 16);
            whi1.x = (unsigned)h4 | ((unsigned)h5 << 16);
            whi1.y = (unsigned)h6 | ((unsigned)h7 << 16);
            wlo0.x = (unsigned)f2bf(p0 - bf2f(h0)) | ((unsigned)f2bf(p1 - bf2f(h1)) << 16);
            wlo0.y = (unsigned)f2bf(p2 - bf2f(h2)) | ((unsigned)f2bf(p3 - bf2f(h3)) << 16);
            wlo1.x = (unsigned)f2bf(p4 - bf2f(h4)) | ((unsigned)f2bf(p5 - bf2f(h5)) << 16);
            wlo1.y = (unsigned)f2bf(p6 - bf2f(h6)) | ((unsigned)f2bf(p7 - bf2f(h7)) << 16);
            *reinterpret_cast<uint2*>(&Pb[w][fl][4 * g])      = whi0;
            *reinterpret_cast<uint2*>(&Pb[w][fl][16 + 4 * g]) = whi1;
            *reinterpret_cast<uint2*>(&Pb[w][fl][32 + 4 * g]) = wlo0;
            *reinterpret_cast<uint2*>(&Pb[w][fl][48 + 4 * g]) = wlo1;

            const bf16x8 BpH = *reinterpret_cast<const bf16x8*>(&Pb[w][fl][8 * g]);
            const bf16x8 BpL = *reinterpret_cast<const bf16x8*>(&Pb[w][fl][32 + 8 * g]);
            accO[j] = __builtin_amdgcn_mfma_f32_16x16x32_bf16(AvH, BpH, accO[j], 0, 0, 0);
            accO[j] = __builtin_amdgcn_mfma_f32_16x16x32_bf16(AvL, BpH, accO[j], 0, 0, 0);
            accO[j] = __builtin_amdgcn_mfma_f32_16x16x32_bf16(AvH, BpL, accO[j], 0, 0, 0);
        }
    }

    #pragma unroll
    for (int j = 0; j < 4; ++j) {
        const int qt = w + 4 * j;
        if (qt > 12) continue;
        const int n = qt * 16 + fl;
        if (n < 196) {
            const float inv = 1.f / lsum[j];
            float4 o;
            o.x = accO[j][0] * inv; o.y = accO[j][1] * inv;
            o.z = accO[j][2] * inv; o.w = accO[j][3] * inv;
            const size_t base = ((size_t)((b * 12 + h) * N_ + n) * 12 + c) * 16 + 4 * g;
            *reinterpret_cast<float4*>(&xs_out[base]) = o;
        }
    }
}

// ---------------------------------------------------------------------------
// Channel attention + outer-product combine -> y' packed ([hi|lo], stride KA)
// ---------------------------------------------------------------------------
__global__ __launch_bounds__(64) void chan_attn_combine(
    const float* __restrict__ qkv,
    const float* __restrict__ xs,
    unsigned short* __restrict__ Yp)
{
    const int bid = blockIdx.x;
    const int n = bid % N_;
    const int h = (bid / N_) % 12;
    const int b = bid / (N_ * 12);
    const int t = threadIdx.x;

    __shared__ float sQ[12][4], sK[12][4], sV[12][4], sXc[12][4];
    __shared__ float sXs[12][16];

    for (int idx = t; idx < 144; idx += 64) {
        const int c = idx / 12, rem = idx % 12, s = rem >> 2, e = rem & 3;
        const float v = qkv[(size_t)((b * N_ + n) * 12 + c) * NQKV_PAD + s * 48 + h * 4 + e];
        if (s == 0) sQ[c][e] = v;
        else if (s == 1) sK[c][e] = v;
        else sV[c][e] = v;
    }
    for (int idx = t; idx < 192; idx += 64) {
        const int c = idx >> 4, j = idx & 15;
        sXs[c][j] = xs[(size_t)(((b * 12 + h) * N_ + n) * 12 + c) * 16 + j];
    }
    __syncthreads();

    if (t < 12) {
        const int c = t;
        float s[12];
        float m = -INFINITY;
        #pragma unroll
        for (int c2 = 0; c2 < 12; ++c2) {
            float d = 0.f;
            #pragma unroll
            for (int e = 0; e < 4; ++e) d += sQ[c][e] * sK[c2][e];
            s[c2] = d * 0.5f;
            m = fmaxf(m, s[c2]);
        }
        float lsum = 0.f;
        #pragma unroll
        for (int c2 = 0; c2 < 12; ++c2) { s[c2] = __expf(s[c2] - m); lsum += s[c2]; }
        const float inv = 1.f / lsum;
        #pragma unroll
        for (int i = 0; i < 4; ++i) {
            float a = 0.f;
            #pragma unroll
            for (int c2 = 0; c2 < 12; ++c2) a += s[c2] * sV[c2][i];
            sXc[c][i] = a * inv;
        }
    }
    __syncthreads();

    const size_t ybase = ((size_t)(b * N_ + n) * 12 + h) * (size_t)KA;
    #pragma unroll
    for (int k = 0; k < 12; ++k) {
        const float v = sXc[k][t >> 4] * sXs[k][t & 15];
        const unsigned short hv = f2bf(v);
        Yp[ybase + k * 64 + t]       = hv;
        Yp[ybase + 768 + k * 64 + t] = f2bf(v - bf2f(hv));
    }
}

// ---------------------------------------------------------------------------
extern "C" void kernel_launch(void* const* d_in, const int* in_sizes, int n_in,
                              void* d_out, int out_size, void* d_ws, size_t ws_size,
                              hipStream_t stream) {
    const float* x       = (const float*)d_in[0];
    const float* w_qkv_c = (const float*)d_in[1];
    const float* w_qkv_s = (const float*)d_in[2];
    const float* w_proj  = (const float*)d_in[3];
    const float* b_proj  = (const float*)d_in[4];
    float* out = (float*)d_out;

    // Workspace (~138 MB):
    //   Ap : MPAD x 1536 bf16 (x packed; aliased as y packed after qkv GEMM;
    //        pad rows never written -> outputs for them never stored)
    //   wqkv_p, wp_p : 768 x 2304 bf16 ; qkv fp32 R x 768 ; xs fp32
    unsigned short* Ap     = (unsigned short*)d_ws;
    unsigned short* wqkv_p = Ap + (size_t)MPAD * KA;
    unsigned short* wp_p   = wqkv_p + (size_t)768 * KP;
    float* qkv = (float*)(wp_p + (size_t)768 * KP);
    float* xs  = qkv + (size_t)R_ * NQKV_PAD;
    unsigned short* Yp = Ap;   // alias: x packed dead after qkv GEMM

    convert_x_p<<<(R_ * 768) / 1024, 256, 0, stream>>>(x, Ap, R_);
    convert_wqkv_p<<<(768 * 768) / 1024, 256, 0, stream>>>(w_qkv_c, w_qkv_s, wqkv_p);
    convert_wp_p<<<(768 * 768) / 1024, 256, 0, stream>>>(w_proj, wp_p);

    const int grid = (MPAD / 256) * 3;   // 74 x 3 = 222
    gemm256_8ph<<<grid, 512, 0, stream>>>(Ap, wqkv_p, nullptr, qkv, R_, NQKV_PAD, 3);
    spatial_attn_mfma<<<B_ * H_ * C_, 256, 0, stream>>>(qkv, xs);
    chan_attn_combine<<<B_ * H_ * N_, 64, 0, stream>>>(qkv, xs, Yp);
    gemm256_8ph<<<grid, 512, 0, stream>>>(Yp, wp_p, b_proj, out, R_, D_, 3);
}

// Round 7
// 268.603 us; speedup vs baseline: 1.2987x; 1.0521x over previous
//
#include <hip/hip_runtime.h>
#include <math.h>

// Problem constants
#define B_  8
#define N_  196
#define C_  12
#define D_  768
#define H_  12
#define R_  (B_*N_*C_)      // 18816 rows
#define KDIM 768
#define NQKV_PAD 768        // 720 real qkv cols padded to 768

typedef __attribute__((ext_vector_type(8))) short bf16x8;   // 8 bf16 = 4 VGPR
typedef __attribute__((ext_vector_type(4))) float f32x4;

__device__ inline unsigned short f2bf(float f) {
    union { float f; unsigned u; } v; v.f = f;
    unsigned r = v.u + 0x7fffu + ((v.u >> 16) & 1u);   // RNE
    return (unsigned short)(r >> 16);
}
__device__ inline float bf2f(unsigned short h) {
    union { unsigned u; float f; } v; v.u = ((unsigned)h) << 16; return v.f;
}

// ---------------------------------------------------------------------------
// fp32 -> (bf16 hi, bf16 lo) elementwise split. n must be a multiple of 4.
// ---------------------------------------------------------------------------
__global__ __launch_bounds__(256) void convert_split(
    const float* __restrict__ in, unsigned short* __restrict__ hi,
    unsigned short* __restrict__ lo, int n)
{
    int i = (blockIdx.x * 256 + threadIdx.x) * 4;
    if (i >= n) return;
    float4 v = *reinterpret_cast<const float4*>(in + i);
    ushort4 h, l;
    h.x = f2bf(v.x); l.x = f2bf(v.x - bf2f(h.x));
    h.y = f2bf(v.y); l.y = f2bf(v.y - bf2f(h.y));
    h.z = f2bf(v.z); l.z = f2bf(v.z - bf2f(h.z));
    h.w = f2bf(v.w); l.w = f2bf(v.w - bf2f(h.w));
    *reinterpret_cast<ushort4*>(hi + i) = h;
    *reinterpret_cast<ushort4*>(lo + i) = l;
}

// One launch for both weight conversions.
// i < 768*768: wqkv (rows: [0,144)=wc, [144,720)=ws, [720,768)=zero)
// else       : wp
__global__ __launch_bounds__(256) void convert_weights(
    const float* __restrict__ wc, const float* __restrict__ ws,
    const float* __restrict__ wp,
    unsigned short* __restrict__ wqkv_hi, unsigned short* __restrict__ wqkv_lo,
    unsigned short* __restrict__ wp_hi,   unsigned short* __restrict__ wp_lo)
{
    int i = (blockIdx.x * 256 + threadIdx.x) * 4;
    unsigned short* dh; unsigned short* dl; float4 v; int off;
    if (i < 768 * 768) {
        const int r = i / 768, k = i % 768;
        v = make_float4(0.f, 0.f, 0.f, 0.f);
        if (r < 144)      v = *reinterpret_cast<const float4*>(wc + r * 768 + k);
        else if (r < 720) v = *reinterpret_cast<const float4*>(ws + (r - 144) * 768 + k);
        dh = wqkv_hi; dl = wqkv_lo; off = i;
    } else {
        off = i - 768 * 768;
        if (off >= 768 * 768) return;
        v = *reinterpret_cast<const float4*>(wp + off);
        dh = wp_hi; dl = wp_lo;
    }
    ushort4 h, l;
    h.x = f2bf(v.x); l.x = f2bf(v.x - bf2f(h.x));
    h.y = f2bf(v.y); l.y = f2bf(v.y - bf2f(h.y));
    h.z = f2bf(v.z); l.z = f2bf(v.z - bf2f(h.z));
    h.w = f2bf(v.w); l.w = f2bf(v.w - bf2f(h.w));
    *reinterpret_cast<ushort4*>(dh + off) = h;
    *reinterpret_cast<ushort4*>(dl + off) = l;
}

// ---------------------------------------------------------------------------
// bf16x3 split MFMA GEMM, 2-phase double-buffered, COUNTED vmcnt (T4) with
// raw barriers, chunked XCD swizzle, nt-fast for A-panel L2 reuse.
// out[M x Nt](fp32) = (Ahi+Alo)[M x K] @ (Bhi+Blo)^T via 3 MFMA terms.
// 128x128 tile, 4 waves x 64x64, BK=32.
// ---------------------------------------------------------------------------
#define BM 128
#define BN 128
#define BK 32

__device__ inline void gload16(const unsigned short* src, void* ldsbase) {
    __builtin_amdgcn_global_load_lds(
        (const __attribute__((address_space(1))) unsigned int*)src,
        (__attribute__((address_space(3))) unsigned int*)ldsbase, 16, 0, 0);
}

__global__ __launch_bounds__(256) void gemm_bf16x3(
    const unsigned short* __restrict__ Ahi, const unsigned short* __restrict__ Alo,
    const unsigned short* __restrict__ Bhi, const unsigned short* __restrict__ Blo,
    const float* __restrict__ bias,
    float* __restrict__ outp, int M, int Nt, int K, int ntiles)
{
    __shared__ unsigned short sAhi[2][BM][BK], sAlo[2][BM][BK];
    __shared__ unsigned short sBhi[2][BN][BK], sBlo[2][BN][BK];

    // chunked bijective XCD swizzle (m204): contiguous logical range per XCD
    const int nwg = gridDim.x;
    const int bid = blockIdx.x;
    const int xcd = bid & 7, slot = bid >> 3;
    const int q = nwg >> 3, r = nwg & 7;
    const int wg = (xcd < r ? xcd * (q + 1) : r * (q + 1) + (xcd - r) * q) + slot;
    const int mt = wg / ntiles, nt = wg - mt * ntiles;   // nt fast: A-panel reuse
    const int m0 = mt * BM, n0 = nt * BN;

    const int tid = threadIdx.x;
    const int w = tid >> 6, l = tid & 63;
    const int wr = (w >> 1) * 64, wc = (w & 1) * 64;

    f32x4 acc[4][4];
    #pragma unroll
    for (int i = 0; i < 4; ++i)
        #pragma unroll
        for (int j = 0; j < 4; ++j)
            acc[i][j] = (f32x4){0.f, 0.f, 0.f, 0.f};

    // staging geometry: one 8KB tile per array per buffer; wave w covers
    // bytes [w*1024,+1024) and [4096+w*1024,+1024); lane adds l*16.
    const int seg0 = w * 1024, seg1 = 4096 + w * 1024;
    const int o0 = seg0 + l * 16, o1 = seg1 + l * 16;
    const int r0 = o0 >> 6, c0 = (o0 & 63) >> 1;
    const int r1 = o1 >> 6, c1 = (o1 & 63) >> 1;

    const int lr = l & 15;
    const int kb = (l >> 4) * 8;

#define STAGE(buf, kk)                                                                     \
    gload16(Ahi + (size_t)(m0 + r0) * K + (kk) + c0, (char*)sAhi + (buf) * 8192 + seg0);   \
    gload16(Ahi + (size_t)(m0 + r1) * K + (kk) + c1, (char*)sAhi + (buf) * 8192 + seg1);   \
    gload16(Alo + (size_t)(m0 + r0) * K + (kk) + c0, (char*)sAlo + (buf) * 8192 + seg0);   \
    gload16(Alo + (size_t)(m0 + r1) * K + (kk) + c1, (char*)sAlo + (buf) * 8192 + seg1);   \
    gload16(Bhi + (size_t)(n0 + r0) * K + (kk) + c0, (char*)sBhi + (buf) * 8192 + seg0);   \
    gload16(Bhi + (size_t)(n0 + r1) * K + (kk) + c1, (char*)sBhi + (buf) * 8192 + seg1);   \
    gload16(Blo + (size_t)(n0 + r0) * K + (kk) + c0, (char*)sBlo + (buf) * 8192 + seg0);   \
    gload16(Blo + (size_t)(n0 + r1) * K + (kk) + c1, (char*)sBlo + (buf) * 8192 + seg1);

    STAGE(0, 0);                       // 8 loads in flight

    const int KT = K / BK;             // 24
    int cur = 0;
    for (int t = 0; t < KT; ++t) {
        if (t + 1 < KT) {
            STAGE(cur ^ 1, (t + 1) * BK);                      // +8 -> 16 in flight
            asm volatile("s_waitcnt vmcnt(8)" ::: "memory");   // drain tile t only
        } else {
            asm volatile("s_waitcnt vmcnt(0)" ::: "memory");   // last tile
        }
        asm volatile("s_barrier" ::: "memory");                // tile t visible to all

        bf16x8 ah[4], al[4];
        #pragma unroll
        for (int fm = 0; fm < 4; ++fm) {
            ah[fm] = *reinterpret_cast<const bf16x8*>(&sAhi[cur][wr + fm * 16 + lr][kb]);
            al[fm] = *reinterpret_cast<const bf16x8*>(&sAlo[cur][wr + fm * 16 + lr][kb]);
        }
        #pragma unroll
        for (int fn = 0; fn < 4; ++fn) {
            bf16x8 bh = *reinterpret_cast<const bf16x8*>(&sBhi[cur][wc + fn * 16 + lr][kb]);
            bf16x8 bl = *reinterpret_cast<const bf16x8*>(&sBlo[cur][wc + fn * 16 + lr][kb]);
            #pragma unroll
            for (int fm = 0; fm < 4; ++fm) {
                acc[fm][fn] = __builtin_amdgcn_mfma_f32_16x16x32_bf16(ah[fm], bh, acc[fm][fn], 0, 0, 0);
                acc[fm][fn] = __builtin_amdgcn_mfma_f32_16x16x32_bf16(ah[fm], bl, acc[fm][fn], 0, 0, 0);
                acc[fm][fn] = __builtin_amdgcn_mfma_f32_16x16x32_bf16(al[fm], bh, acc[fm][fn], 0, 0, 0);
            }
        }
        // write-after-read fence: all ds_reads of [cur] were consumed by MFMAs
        // (compiler lgkm waits) before this barrier; next STAGE targets [cur].
        asm volatile("s_barrier" ::: "memory");
        cur ^= 1;
    }
#undef STAGE

    const int rg = (l >> 4) * 4;
    #pragma unroll
    for (int fm = 0; fm < 4; ++fm) {
        #pragma unroll
        for (int fn = 0; fn < 4; ++fn) {
            const int row = m0 + wr + fm * 16 + rg;
            const int col = n0 + wc + fn * 16 + lr;
            const float bv = bias ? bias[col] : 0.f;
            #pragma unroll
            for (int rr = 0; rr < 4; ++rr)
                outp[(size_t)(row + rr) * Nt + col] = acc[fm][fn][rr] + bv;
        }
    }
}

// ---------------------------------------------------------------------------
// MFMA spatial attention (unchanged, verified).
// ---------------------------------------------------------------------------
__global__ __launch_bounds__(256) void spatial_attn_mfma(
    const float* __restrict__ qkv,
    float* __restrict__ xs_out)
{
    __shared__ unsigned short Kl[224][32];
    __shared__ unsigned short Ql[208][40];
    __shared__ unsigned short VtH[16][224];
    __shared__ unsigned short VtL[16][224];
    __shared__ unsigned short Pb[4][16][72];

    const int bid = blockIdx.x;                // 1152 = 8*12*12
    const int c = bid % 12;
    const int h = (bid / 12) % 12;
    const int b = bid / 144;
    const int tid = threadIdx.x;
    const int w = tid >> 6, l = tid & 63;
    const int fl = l & 15, g = l >> 4;

    for (int idx = tid; idx < N_ * 16; idx += 256) {
        const int n = idx >> 4, e = idx & 15;
        const float* base = qkv + (size_t)((b * N_ + n) * 12 + c) * NQKV_PAD + 144 + h * 16 + e;
        const float qv = base[0] * 0.25f;
        const float kv = base[192];
        const float vv = base[384];
        const unsigned short qh = f2bf(qv), kh = f2bf(kv), vh = f2bf(vv);
        Ql[n][e]      = qh;  Ql[n][16 + e] = f2bf(qv - bf2f(qh));
        Kl[n][e]      = kh;  Kl[n][16 + e] = f2bf(kv - bf2f(kh));
        VtH[e][n]     = vh;  VtL[e][n]     = f2bf(vv - bf2f(vh));
    }
    for (int idx = tid; idx < 16 * 28; idx += 256) {
        const int d = idx / 28, n = 196 + idx % 28;
        VtH[d][n] = 0; VtL[d][n] = 0;
    }
    __syncthreads();

    f32x4 accO[4];
    float mrun[4], lsum[4];
    #pragma unroll
    for (int j = 0; j < 4; ++j) {
        accO[j] = (f32x4){0.f, 0.f, 0.f, 0.f};
        mrun[j] = -INFINITY; lsum[j] = 0.f;
    }
    const f32x4 zf = (f32x4){0.f, 0.f, 0.f, 0.f};
    const bf16x8 zb = (bf16x8){0, 0, 0, 0, 0, 0, 0, 0};

    for (int ch = 0; ch < 7; ++ch) {
        const int kb0 = ch * 32;
        const bf16x8 A1a = *reinterpret_cast<const bf16x8*>(&Kl[kb0 + fl][8 * g]);
        const bf16x8 A1b = *reinterpret_cast<const bf16x8*>(&Kl[kb0 + 16 + fl][8 * g]);
        const bf16x8 A2a = *reinterpret_cast<const bf16x8*>(&Kl[kb0 + fl][8 * (g & 1)]);
        const bf16x8 A2b = *reinterpret_cast<const bf16x8*>(&Kl[kb0 + 16 + fl][8 * (g & 1)]);
        const bf16x8 AvH = *reinterpret_cast<const bf16x8*>(&VtH[fl][kb0 + 8 * g]);
        const bf16x8 AvL = *reinterpret_cast<const bf16x8*>(&VtL[fl][kb0 + 8 * g]);

        #pragma unroll
        for (int j = 0; j < 4; ++j) {
            const int qt = w + 4 * j;
            if (qt > 12) continue;
            const int qrow = qt * 16 + fl;
            const bf16x8 Bq1 = *reinterpret_cast<const bf16x8*>(&Ql[qrow][8 * (g & 1)]);
            bf16x8 Bq2 = *reinterpret_cast<const bf16x8*>(&Ql[qrow][16 + 8 * (g & 1)]);
            if (g >= 2) Bq2 = zb;

            f32x4 T0 = zf, T1 = zf;
            T0 = __builtin_amdgcn_mfma_f32_16x16x32_bf16(A1a, Bq1, T0, 0, 0, 0);
            T0 = __builtin_amdgcn_mfma_f32_16x16x32_bf16(A2a, Bq2, T0, 0, 0, 0);
            T1 = __builtin_amdgcn_mfma_f32_16x16x32_bf16(A1b, Bq1, T1, 0, 0, 0);
            T1 = __builtin_amdgcn_mfma_f32_16x16x32_bf16(A2b, Bq2, T1, 0, 0, 0);

            float s0 = T0[0], s1 = T0[1], s2 = T0[2], s3 = T0[3];
            float s4 = T1[0], s5 = T1[1], s6 = T1[2], s7 = T1[3];
            if (ch == 6) {
                const int kg = kb0 + 4 * g;
                if (kg + 0 >= 196) s0 = -1e30f;
                if (kg + 1 >= 196) s1 = -1e30f;
                if (kg + 2 >= 196) s2 = -1e30f;
                if (kg + 3 >= 196) s3 = -1e30f;
                s4 = -1e30f; s5 = -1e30f; s6 = -1e30f; s7 = -1e30f;
            }
            float cm = fmaxf(fmaxf(fmaxf(s0, s1), fmaxf(s2, s3)),
                             fmaxf(fmaxf(s4, s5), fmaxf(s6, s7)));
            cm = fmaxf(cm, __shfl_xor(cm, 16));
            cm = fmaxf(cm, __shfl_xor(cm, 32));
            const float mn = fmaxf(mrun[j], cm);
            const float corr = __expf(mrun[j] - mn);
            mrun[j] = mn;
            const float p0 = __expf(s0 - mn), p1 = __expf(s1 - mn);
            const float p2 = __expf(s2 - mn), p3 = __expf(s3 - mn);
            const float p4 = __expf(s4 - mn), p5 = __expf(s5 - mn);
            const float p6 = __expf(s6 - mn), p7 = __expf(s7 - mn);
            float ps = ((p0 + p1) + (p2 + p3)) + ((p4 + p5) + (p6 + p7));
            ps += __shfl_xor(ps, 16);
            ps += __shfl_xor(ps, 32);
            lsum[j] = lsum[j] * corr + ps;
            accO[j][0] *= corr; accO[j][1] *= corr;
            accO[j][2] *= corr; accO[j][3] *= corr;

            unsigned short h0 = f2bf(p0), h1 = f2bf(p1), h2 = f2bf(p2), h3 = f2bf(p3);
            unsigned short h4 = f2bf(p4), h5 = f2bf(p5), h6 = f2bf(p6), h7 = f2bf(p7);
            uint2 whi0, whi1, wlo0, wlo1;
            whi0.x = (unsigned)h0 | ((unsigned)h1 << 16);
            whi0.y = (unsigned)h2 | ((unsigned)h3 << 16);
            whi1.x = (unsigned)h4 | ((unsigned)h5 << 16);
            whi1.y = (unsigned)h6 | ((unsigned)h7 << 16);
            wlo0.x = (unsigned)f2bf(p0 - bf2f(h0)) | ((unsigned)f2bf(p1 - bf2f(h1)) << 16);
            wlo0.y = (unsigned)f2bf(p2 - bf2f(h2)) | ((unsigned)f2bf(p3 - bf2f(h3)) << 16);
            wlo1.x = (unsigned)f2bf(p4 - bf2f(h4)) | ((unsigned)f2bf(p5 - bf2f(h5)) << 16);
            wlo1.y = (unsigned)f2bf(p6 - bf2f(h6)) | ((unsigned)f2bf(p7 - bf2f(h7)) << 16);
            *reinterpret_cast<uint2*>(&Pb[w][fl][4 * g])      = whi0;
            *reinterpret_cast<uint2*>(&Pb[w][fl][16 + 4 * g]) = whi1;
            *reinterpret_cast<uint2*>(&Pb[w][fl][32 + 4 * g]) = wlo0;
            *reinterpret_cast<uint2*>(&Pb[w][fl][48 + 4 * g]) = wlo1;

            const bf16x8 BpH = *reinterpret_cast<const bf16x8*>(&Pb[w][fl][8 * g]);
            const bf16x8 BpL = *reinterpret_cast<const bf16x8*>(&Pb[w][fl][32 + 8 * g]);
            accO[j] = __builtin_amdgcn_mfma_f32_16x16x32_bf16(AvH, BpH, accO[j], 0, 0, 0);
            accO[j] = __builtin_amdgcn_mfma_f32_16x16x32_bf16(AvL, BpH, accO[j], 0, 0, 0);
            accO[j] = __builtin_amdgcn_mfma_f32_16x16x32_bf16(AvH, BpL, accO[j], 0, 0, 0);
        }
    }

    #pragma unroll
    for (int j = 0; j < 4; ++j) {
        const int qt = w + 4 * j;
        if (qt > 12) continue;
        const int n = qt * 16 + fl;
        if (n < 196) {
            const float inv = 1.f / lsum[j];
            float4 o;
            o.x = accO[j][0] * inv; o.y = accO[j][1] * inv;
            o.z = accO[j][2] * inv; o.w = accO[j][3] * inv;
            const size_t base = ((size_t)((b * 12 + h) * N_ + n) * 12 + c) * 16 + 4 * g;
            *reinterpret_cast<float4*>(&xs_out[base]) = o;
        }
    }
}

// ---------------------------------------------------------------------------
// Channel attention + outer-product combine, 4 rows per 256-thread block.
// flat = (b*12+h)*196 + n; sub-block = one flat row per 64 lanes.
// ---------------------------------------------------------------------------
__global__ __launch_bounds__(256) void chan_attn_combine4(
    const float* __restrict__ qkv,
    const float* __restrict__ xs,
    unsigned short* __restrict__ yhi,
    unsigned short* __restrict__ ylo)
{
    const int sub = threadIdx.x >> 6;
    const int t = threadIdx.x & 63;
    const int flat = blockIdx.x * 4 + sub;     // (b*12+h)*196 + n
    const int n = flat % 196;
    const int h = (flat / 196) % 12;
    const int b = flat / 2352;

    __shared__ float sQ[4][12][4], sK[4][12][4], sV[4][12][4], sXc[4][12][4];
    __shared__ float sXs[4][12][16];

    for (int idx = t; idx < 144; idx += 64) {
        const int c = idx / 12, rem = idx % 12, s = rem >> 2, e = rem & 3;
        const float v = qkv[(size_t)((b * N_ + n) * 12 + c) * NQKV_PAD + s * 48 + h * 4 + e];
        if (s == 0) sQ[sub][c][e] = v;
        else if (s == 1) sK[sub][c][e] = v;
        else sV[sub][c][e] = v;
    }
    for (int idx = t; idx < 192; idx += 64) {
        const int c = idx >> 4, j = idx & 15;
        sXs[sub][c][j] = xs[((size_t)flat * 12 + c) * 16 + j];
    }
    __syncthreads();

    if (t < 12) {
        const int c = t;
        float s[12];
        float m = -INFINITY;
        #pragma unroll
        for (int c2 = 0; c2 < 12; ++c2) {
            float d = 0.f;
            #pragma unroll
            for (int e = 0; e < 4; ++e) d += sQ[sub][c][e] * sK[sub][c2][e];
            s[c2] = d * 0.5f;
            m = fmaxf(m, s[c2]);
        }
        float lsum = 0.f;
        #pragma unroll
        for (int c2 = 0; c2 < 12; ++c2) { s[c2] = __expf(s[c2] - m); lsum += s[c2]; }
        const float inv = 1.f / lsum;
        #pragma unroll
        for (int i = 0; i < 4; ++i) {
            float a = 0.f;
            #pragma unroll
            for (int c2 = 0; c2 < 12; ++c2) a += s[c2] * sV[sub][c2][i];
            sXc[sub][c][i] = a * inv;
        }
    }
    __syncthreads();

    const size_t yrow = ((size_t)(b * N_ + n) * 12 + h) * (size_t)D_;
    #pragma unroll
    for (int k = 0; k < 12; ++k) {
        const float v = sXc[sub][k][t >> 4] * sXs[sub][k][t & 15];
        const unsigned short hv = f2bf(v);
        yhi[yrow + k * 64 + t] = hv;
        ylo[yrow + k * 64 + t] = f2bf(v - bf2f(hv));
    }
}

// ---------------------------------------------------------------------------
extern "C" void kernel_launch(void* const* d_in, const int* in_sizes, int n_in,
                              void* d_out, int out_size, void* d_ws, size_t ws_size,
                              hipStream_t stream) {
    const float* x       = (const float*)d_in[0];
    const float* w_qkv_c = (const float*)d_in[1];
    const float* w_qkv_s = (const float*)d_in[2];
    const float* w_proj  = (const float*)d_in[3];
    const float* b_proj  = (const float*)d_in[4];
    float* out = (float*)d_out;

    unsigned short* xhi = (unsigned short*)d_ws;
    unsigned short* xlo = xhi + (size_t)R_ * KDIM;
    unsigned short* wqkv_hi = xlo + (size_t)R_ * KDIM;
    unsigned short* wqkv_lo = wqkv_hi + (size_t)768 * 768;
    unsigned short* wp_hi   = wqkv_lo + (size_t)768 * 768;
    unsigned short* wp_lo   = wp_hi + (size_t)768 * 768;
    float* qkv = (float*)(wp_lo + (size_t)768 * 768);
    float* xs  = qkv + (size_t)R_ * NQKV_PAD;
    unsigned short* yhi = xhi;   // alias: x splits dead after qkv GEMM
    unsigned short* ylo = xlo;

    convert_split<<<(R_ * KDIM) / 1024, 256, 0, stream>>>(x, xhi, xlo, R_ * KDIM);
    convert_weights<<<(2 * 768 * 768) / 1024, 256, 0, stream>>>(
        w_qkv_c, w_qkv_s, w_proj, wqkv_hi, wqkv_lo, wp_hi, wp_lo);

    {
        const int mtiles = R_ / BM, ntiles = NQKV_PAD / BN;
        gemm_bf16x3<<<mtiles * ntiles, 256, 0, stream>>>(
            xhi, xlo, wqkv_hi, wqkv_lo, nullptr, qkv, R_, NQKV_PAD, KDIM, ntiles);
    }
    spatial_attn_mfma<<<B_ * H_ * C_, 256, 0, stream>>>(qkv, xs);
    chan_attn_combine4<<<(B_ * H_ * N_) / 4, 256, 0, stream>>>(qkv, xs, yhi, ylo);
    {
        const int mtiles = R_ / BM, ntiles = D_ / BN;
        gemm_bf16x3<<<mtiles * ntiles, 256, 0, stream>>>(
            yhi, ylo, wp_hi, wp_lo, b_proj, out, R_, D_, KDIM, ntiles);
    }
}

// Round 8
// 265.708 us; speedup vs baseline: 1.3128x; 1.0109x over previous
//
#include <hip/hip_runtime.h>
#include <math.h>

// Problem constants
#define B_  8
#define N_  196
#define C_  12
#define D_  768
#define H_  12
#define R_  (B_*N_*C_)      // 18816 rows
#define KDIM 768
#define NQKV_PAD 768        // 720 real qkv cols padded to 768

typedef __attribute__((ext_vector_type(8))) short bf16x8;   // 8 bf16 = 4 VGPR
typedef __attribute__((ext_vector_type(4))) float f32x4;

__device__ inline unsigned short f2bf(float f) {
    union { float f; unsigned u; } v; v.f = f;
    unsigned r = v.u + 0x7fffu + ((v.u >> 16) & 1u);   // RNE
    return (unsigned short)(r >> 16);
}
__device__ inline float bf2f(unsigned short h) {
    union { unsigned u; float f; } v; v.u = ((unsigned)h) << 16; return v.f;
}

// ---------------------------------------------------------------------------
// fp32 -> (bf16 hi, bf16 lo) elementwise split. n must be a multiple of 4.
// ---------------------------------------------------------------------------
__global__ __launch_bounds__(256) void convert_split(
    const float* __restrict__ in, unsigned short* __restrict__ hi,
    unsigned short* __restrict__ lo, int n)
{
    int i = (blockIdx.x * 256 + threadIdx.x) * 4;
    if (i >= n) return;
    float4 v = *reinterpret_cast<const float4*>(in + i);
    ushort4 h, l;
    h.x = f2bf(v.x); l.x = f2bf(v.x - bf2f(h.x));
    h.y = f2bf(v.y); l.y = f2bf(v.y - bf2f(h.y));
    h.z = f2bf(v.z); l.z = f2bf(v.z - bf2f(h.z));
    h.w = f2bf(v.w); l.w = f2bf(v.w - bf2f(h.w));
    *reinterpret_cast<ushort4*>(hi + i) = h;
    *reinterpret_cast<ushort4*>(lo + i) = l;
}

// One launch for both weight conversions.
__global__ __launch_bounds__(256) void convert_weights(
    const float* __restrict__ wc, const float* __restrict__ ws,
    const float* __restrict__ wp,
    unsigned short* __restrict__ wqkv_hi, unsigned short* __restrict__ wqkv_lo,
    unsigned short* __restrict__ wp_hi,   unsigned short* __restrict__ wp_lo)
{
    int i = (blockIdx.x * 256 + threadIdx.x) * 4;
    unsigned short* dh; unsigned short* dl; float4 v; int off;
    if (i < 768 * 768) {
        const int r = i / 768, k = i % 768;
        v = make_float4(0.f, 0.f, 0.f, 0.f);
        if (r < 144)      v = *reinterpret_cast<const float4*>(wc + r * 768 + k);
        else if (r < 720) v = *reinterpret_cast<const float4*>(ws + (r - 144) * 768 + k);
        dh = wqkv_hi; dl = wqkv_lo; off = i;
    } else {
        off = i - 768 * 768;
        if (off >= 768 * 768) return;
        v = *reinterpret_cast<const float4*>(wp + off);
        dh = wp_hi; dl = wp_lo;
    }
    ushort4 h, l;
    h.x = f2bf(v.x); l.x = f2bf(v.x - bf2f(h.x));
    h.y = f2bf(v.y); l.y = f2bf(v.y - bf2f(h.y));
    h.z = f2bf(v.z); l.z = f2bf(v.z - bf2f(h.z));
    h.w = f2bf(v.w); l.w = f2bf(v.w - bf2f(h.w));
    *reinterpret_cast<ushort4*>(dh + off) = h;
    *reinterpret_cast<ushort4*>(dl + off) = l;
}

// ---------------------------------------------------------------------------
// bf16x3 split MFMA GEMM (round-7 verified: 2-phase dbuf, counted vmcnt,
// chunked XCD swizzle, nt-fast). Unchanged.
// ---------------------------------------------------------------------------
#define BM 128
#define BN 128
#define BK 32

__device__ inline void gload16(const unsigned short* src, void* ldsbase) {
    __builtin_amdgcn_global_load_lds(
        (const __attribute__((address_space(1))) unsigned int*)src,
        (__attribute__((address_space(3))) unsigned int*)ldsbase, 16, 0, 0);
}

__global__ __launch_bounds__(256) void gemm_bf16x3(
    const unsigned short* __restrict__ Ahi, const unsigned short* __restrict__ Alo,
    const unsigned short* __restrict__ Bhi, const unsigned short* __restrict__ Blo,
    const float* __restrict__ bias,
    float* __restrict__ outp, int M, int Nt, int K, int ntiles)
{
    __shared__ unsigned short sAhi[2][BM][BK], sAlo[2][BM][BK];
    __shared__ unsigned short sBhi[2][BN][BK], sBlo[2][BN][BK];

    const int nwg = gridDim.x;
    const int bid = blockIdx.x;
    const int xcd = bid & 7, slot = bid >> 3;
    const int q = nwg >> 3, r = nwg & 7;
    const int wg = (xcd < r ? xcd * (q + 1) : r * (q + 1) + (xcd - r) * q) + slot;
    const int mt = wg / ntiles, nt = wg - mt * ntiles;
    const int m0 = mt * BM, n0 = nt * BN;

    const int tid = threadIdx.x;
    const int w = tid >> 6, l = tid & 63;
    const int wr = (w >> 1) * 64, wc = (w & 1) * 64;

    f32x4 acc[4][4];
    #pragma unroll
    for (int i = 0; i < 4; ++i)
        #pragma unroll
        for (int j = 0; j < 4; ++j)
            acc[i][j] = (f32x4){0.f, 0.f, 0.f, 0.f};

    const int seg0 = w * 1024, seg1 = 4096 + w * 1024;
    const int o0 = seg0 + l * 16, o1 = seg1 + l * 16;
    const int r0 = o0 >> 6, c0 = (o0 & 63) >> 1;
    const int r1 = o1 >> 6, c1 = (o1 & 63) >> 1;

    const int lr = l & 15;
    const int kb = (l >> 4) * 8;

#define STAGE(buf, kk)                                                                     \
    gload16(Ahi + (size_t)(m0 + r0) * K + (kk) + c0, (char*)sAhi + (buf) * 8192 + seg0);   \
    gload16(Ahi + (size_t)(m0 + r1) * K + (kk) + c1, (char*)sAhi + (buf) * 8192 + seg1);   \
    gload16(Alo + (size_t)(m0 + r0) * K + (kk) + c0, (char*)sAlo + (buf) * 8192 + seg0);   \
    gload16(Alo + (size_t)(m0 + r1) * K + (kk) + c1, (char*)sAlo + (buf) * 8192 + seg1);   \
    gload16(Bhi + (size_t)(n0 + r0) * K + (kk) + c0, (char*)sBhi + (buf) * 8192 + seg0);   \
    gload16(Bhi + (size_t)(n0 + r1) * K + (kk) + c1, (char*)sBhi + (buf) * 8192 + seg1);   \
    gload16(Blo + (size_t)(n0 + r0) * K + (kk) + c0, (char*)sBlo + (buf) * 8192 + seg0);   \
    gload16(Blo + (size_t)(n0 + r1) * K + (kk) + c1, (char*)sBlo + (buf) * 8192 + seg1);

    STAGE(0, 0);

    const int KT = K / BK;
    int cur = 0;
    for (int t = 0; t < KT; ++t) {
        if (t + 1 < KT) {
            STAGE(cur ^ 1, (t + 1) * BK);
            asm volatile("s_waitcnt vmcnt(8)" ::: "memory");
        } else {
            asm volatile("s_waitcnt vmcnt(0)" ::: "memory");
        }
        asm volatile("s_barrier" ::: "memory");

        bf16x8 ah[4], al[4];
        #pragma unroll
        for (int fm = 0; fm < 4; ++fm) {
            ah[fm] = *reinterpret_cast<const bf16x8*>(&sAhi[cur][wr + fm * 16 + lr][kb]);
            al[fm] = *reinterpret_cast<const bf16x8*>(&sAlo[cur][wr + fm * 16 + lr][kb]);
        }
        #pragma unroll
        for (int fn = 0; fn < 4; ++fn) {
            bf16x8 bh = *reinterpret_cast<const bf16x8*>(&sBhi[cur][wc + fn * 16 + lr][kb]);
            bf16x8 bl = *reinterpret_cast<const bf16x8*>(&sBlo[cur][wc + fn * 16 + lr][kb]);
            #pragma unroll
            for (int fm = 0; fm < 4; ++fm) {
                acc[fm][fn] = __builtin_amdgcn_mfma_f32_16x16x32_bf16(ah[fm], bh, acc[fm][fn], 0, 0, 0);
                acc[fm][fn] = __builtin_amdgcn_mfma_f32_16x16x32_bf16(ah[fm], bl, acc[fm][fn], 0, 0, 0);
                acc[fm][fn] = __builtin_amdgcn_mfma_f32_16x16x32_bf16(al[fm], bh, acc[fm][fn], 0, 0, 0);
            }
        }
        asm volatile("s_barrier" ::: "memory");
        cur ^= 1;
    }
#undef STAGE

    const int rg = (l >> 4) * 4;
    #pragma unroll
    for (int fm = 0; fm < 4; ++fm) {
        #pragma unroll
        for (int fn = 0; fn < 4; ++fn) {
            const int row = m0 + wr + fm * 16 + rg;
            const int col = n0 + wc + fn * 16 + lr;
            const float bv = bias ? bias[col] : 0.f;
            #pragma unroll
            for (int rr = 0; rr < 4; ++rr)
                outp[(size_t)(row + rr) * Nt + col] = acc[fm][fn][rr] + bv;
        }
    }
}

// ---------------------------------------------------------------------------
// MFMA spatial attention. THIS ROUND: LDS bank-conflict fix only.
//   Kl : [224][32] -> [224][40]  (stride 80B = 20 dw, gcd(20,32)=4 -> 2-way)
//   Vt : [16][224] -> [16][232]  (stride 464B = 116 dw ≡ 20 mod 32 -> 2-way)
// (Ql stride 80B and Pb stride 144B were already 2-way.)  2-way is free (m136).
// ---------------------------------------------------------------------------
__global__ __launch_bounds__(256) void spatial_attn_mfma(
    const float* __restrict__ qkv,
    float* __restrict__ xs_out)
{
    __shared__ unsigned short Kl[224][40];     // cols: Khi(0..15) Klo(16..31) pad
    __shared__ unsigned short Ql[208][40];     // cols: Qhi(0..15) Qlo(16..31) pad
    __shared__ unsigned short VtH[16][232];    // V^T hi: [d][k], pad cols
    __shared__ unsigned short VtL[16][232];
    __shared__ unsigned short Pb[4][16][72];   // per-wave: [q][Phi(32)|Plo(32)|pad]

    const int bid = blockIdx.x;                // 1152 = 8*12*12
    const int c = bid % 12;
    const int h = (bid / 12) % 12;
    const int b = bid / 144;
    const int tid = threadIdx.x;
    const int w = tid >> 6, l = tid & 63;
    const int fl = l & 15, g = l >> 4;

    for (int idx = tid; idx < N_ * 16; idx += 256) {
        const int n = idx >> 4, e = idx & 15;
        const float* base = qkv + (size_t)((b * N_ + n) * 12 + c) * NQKV_PAD + 144 + h * 16 + e;
        const float qv = base[0] * 0.25f;
        const float kv = base[192];
        const float vv = base[384];
        const unsigned short qh = f2bf(qv), kh = f2bf(kv), vh = f2bf(vv);
        Ql[n][e]      = qh;  Ql[n][16 + e] = f2bf(qv - bf2f(qh));
        Kl[n][e]      = kh;  Kl[n][16 + e] = f2bf(kv - bf2f(kh));
        VtH[e][n]     = vh;  VtL[e][n]     = f2bf(vv - bf2f(vh));
    }
    for (int idx = tid; idx < 16 * 28; idx += 256) {
        const int d = idx / 28, n = 196 + idx % 28;
        VtH[d][n] = 0; VtL[d][n] = 0;
    }
    __syncthreads();

    f32x4 accO[4];
    float mrun[4], lsum[4];
    #pragma unroll
    for (int j = 0; j < 4; ++j) {
        accO[j] = (f32x4){0.f, 0.f, 0.f, 0.f};
        mrun[j] = -INFINITY; lsum[j] = 0.f;
    }
    const f32x4 zf = (f32x4){0.f, 0.f, 0.f, 0.f};
    const bf16x8 zb = (bf16x8){0, 0, 0, 0, 0, 0, 0, 0};

    for (int ch = 0; ch < 7; ++ch) {
        const int kb0 = ch * 32;
        const bf16x8 A1a = *reinterpret_cast<const bf16x8*>(&Kl[kb0 + fl][8 * g]);
        const bf16x8 A1b = *reinterpret_cast<const bf16x8*>(&Kl[kb0 + 16 + fl][8 * g]);
        const bf16x8 A2a = *reinterpret_cast<const bf16x8*>(&Kl[kb0 + fl][8 * (g & 1)]);
        const bf16x8 A2b = *reinterpret_cast<const bf16x8*>(&Kl[kb0 + 16 + fl][8 * (g & 1)]);
        const bf16x8 AvH = *reinterpret_cast<const bf16x8*>(&VtH[fl][kb0 + 8 * g]);
        const bf16x8 AvL = *reinterpret_cast<const bf16x8*>(&VtL[fl][kb0 + 8 * g]);

        #pragma unroll
        for (int j = 0; j < 4; ++j) {
            const int qt = w + 4 * j;
            if (qt > 12) continue;
            const int qrow = qt * 16 + fl;
            const bf16x8 Bq1 = *reinterpret_cast<const bf16x8*>(&Ql[qrow][8 * (g & 1)]);
            bf16x8 Bq2 = *reinterpret_cast<const bf16x8*>(&Ql[qrow][16 + 8 * (g & 1)]);
            if (g >= 2) Bq2 = zb;

            f32x4 T0 = zf, T1 = zf;
            T0 = __builtin_amdgcn_mfma_f32_16x16x32_bf16(A1a, Bq1, T0, 0, 0, 0);
            T0 = __builtin_amdgcn_mfma_f32_16x16x32_bf16(A2a, Bq2, T0, 0, 0, 0);
            T1 = __builtin_amdgcn_mfma_f32_16x16x32_bf16(A1b, Bq1, T1, 0, 0, 0);
            T1 = __builtin_amdgcn_mfma_f32_16x16x32_bf16(A2b, Bq2, T1, 0, 0, 0);

            float s0 = T0[0], s1 = T0[1], s2 = T0[2], s3 = T0[3];
            float s4 = T1[0], s5 = T1[1], s6 = T1[2], s7 = T1[3];
            if (ch == 6) {
                const int kg = kb0 + 4 * g;
                if (kg + 0 >= 196) s0 = -1e30f;
                if (kg + 1 >= 196) s1 = -1e30f;
                if (kg + 2 >= 196) s2 = -1e30f;
                if (kg + 3 >= 196) s3 = -1e30f;
                s4 = -1e30f; s5 = -1e30f; s6 = -1e30f; s7 = -1e30f;
            }
            float cm = fmaxf(fmaxf(fmaxf(s0, s1), fmaxf(s2, s3)),
                             fmaxf(fmaxf(s4, s5), fmaxf(s6, s7)));
            cm = fmaxf(cm, __shfl_xor(cm, 16));
            cm = fmaxf(cm, __shfl_xor(cm, 32));
            const float mn = fmaxf(mrun[j], cm);
            const float corr = __expf(mrun[j] - mn);
            mrun[j] = mn;
            const float p0 = __expf(s0 - mn), p1 = __expf(s1 - mn);
            const float p2 = __expf(s2 - mn), p3 = __expf(s3 - mn);
            const float p4 = __expf(s4 - mn), p5 = __expf(s5 - mn);
            const float p6 = __expf(s6 - mn), p7 = __expf(s7 - mn);
            float ps = ((p0 + p1) + (p2 + p3)) + ((p4 + p5) + (p6 + p7));
            ps += __shfl_xor(ps, 16);
            ps += __shfl_xor(ps, 32);
            lsum[j] = lsum[j] * corr + ps;
            accO[j][0] *= corr; accO[j][1] *= corr;
            accO[j][2] *= corr; accO[j][3] *= corr;

            unsigned short h0 = f2bf(p0), h1 = f2bf(p1), h2 = f2bf(p2), h3 = f2bf(p3);
            unsigned short h4 = f2bf(p4), h5 = f2bf(p5), h6 = f2bf(p6), h7 = f2bf(p7);
            uint2 whi0, whi1, wlo0, wlo1;
            whi0.x = (unsigned)h0 | ((unsigned)h1 << 16);
            whi0.y = (unsigned)h2 | ((unsigned)h3 << 16);
            whi1.x = (unsigned)h4 | ((unsigned)h5 << 16);
            whi1.y = (unsigned)h6 | ((unsigned)h7 << 16);
            wlo0.x = (unsigned)f2bf(p0 - bf2f(h0)) | ((unsigned)f2bf(p1 - bf2f(h1)) << 16);
            wlo0.y = (unsigned)f2bf(p2 - bf2f(h2)) | ((unsigned)f2bf(p3 - bf2f(h3)) << 16);
            wlo1.x = (unsigned)f2bf(p4 - bf2f(h4)) | ((unsigned)f2bf(p5 - bf2f(h5)) << 16);
            wlo1.y = (unsigned)f2bf(p6 - bf2f(h6)) | ((unsigned)f2bf(p7 - bf2f(h7)) << 16);
            *reinterpret_cast<uint2*>(&Pb[w][fl][4 * g])      = whi0;
            *reinterpret_cast<uint2*>(&Pb[w][fl][16 + 4 * g]) = whi1;
            *reinterpret_cast<uint2*>(&Pb[w][fl][32 + 4 * g]) = wlo0;
            *reinterpret_cast<uint2*>(&Pb[w][fl][48 + 4 * g]) = wlo1;

            const bf16x8 BpH = *reinterpret_cast<const bf16x8*>(&Pb[w][fl][8 * g]);
            const bf16x8 BpL = *reinterpret_cast<const bf16x8*>(&Pb[w][fl][32 + 8 * g]);
            accO[j] = __builtin_amdgcn_mfma_f32_16x16x32_bf16(AvH, BpH, accO[j], 0, 0, 0);
            accO[j] = __builtin_amdgcn_mfma_f32_16x16x32_bf16(AvL, BpH, accO[j], 0, 0, 0);
            accO[j] = __builtin_amdgcn_mfma_f32_16x16x32_bf16(AvH, BpL, accO[j], 0, 0, 0);
        }
    }

    #pragma unroll
    for (int j = 0; j < 4; ++j) {
        const int qt = w + 4 * j;
        if (qt > 12) continue;
        const int n = qt * 16 + fl;
        if (n < 196) {
            const float inv = 1.f / lsum[j];
            float4 o;
            o.x = accO[j][0] * inv; o.y = accO[j][1] * inv;
            o.z = accO[j][2] * inv; o.w = accO[j][3] * inv;
            const size_t base = ((size_t)((b * 12 + h) * N_ + n) * 12 + c) * 16 + 4 * g;
            *reinterpret_cast<float4*>(&xs_out[base]) = o;
        }
    }
}

// ---------------------------------------------------------------------------
// Channel attention + outer-product combine, 4 rows per 256-thread block.
// ---------------------------------------------------------------------------
__global__ __launch_bounds__(256) void chan_attn_combine4(
    const float* __restrict__ qkv,
    const float* __restrict__ xs,
    unsigned short* __restrict__ yhi,
    unsigned short* __restrict__ ylo)
{
    const int sub = threadIdx.x >> 6;
    const int t = threadIdx.x & 63;
    const int flat = blockIdx.x * 4 + sub;     // (b*12+h)*196 + n
    const int n = flat % 196;
    const int h = (flat / 196) % 12;
    const int b = flat / 2352;

    __shared__ float sQ[4][12][4], sK[4][12][4], sV[4][12][4], sXc[4][12][4];
    __shared__ float sXs[4][12][16];

    for (int idx = t; idx < 144; idx += 64) {
        const int c = idx / 12, rem = idx % 12, s = rem >> 2, e = rem & 3;
        const float v = qkv[(size_t)((b * N_ + n) * 12 + c) * NQKV_PAD + s * 48 + h * 4 + e];
        if (s == 0) sQ[sub][c][e] = v;
        else if (s == 1) sK[sub][c][e] = v;
        else sV[sub][c][e] = v;
    }
    for (int idx = t; idx < 192; idx += 64) {
        const int c = idx >> 4, j = idx & 15;
        sXs[sub][c][j] = xs[((size_t)flat * 12 + c) * 16 + j];
    }
    __syncthreads();

    if (t < 12) {
        const int c = t;
        float s[12];
        float m = -INFINITY;
        #pragma unroll
        for (int c2 = 0; c2 < 12; ++c2) {
            float d = 0.f;
            #pragma unroll
            for (int e = 0; e < 4; ++e) d += sQ[sub][c][e] * sK[sub][c2][e];
            s[c2] = d * 0.5f;
            m = fmaxf(m, s[c2]);
        }
        float lsum = 0.f;
        #pragma unroll
        for (int c2 = 0; c2 < 12; ++c2) { s[c2] = __expf(s[c2] - m); lsum += s[c2]; }
        const float inv = 1.f / lsum;
        #pragma unroll
        for (int i = 0; i < 4; ++i) {
            float a = 0.f;
            #pragma unroll
            for (int c2 = 0; c2 < 12; ++c2) a += s[c2] * sV[sub][c2][i];
            sXc[sub][c][i] = a * inv;
        }
    }
    __syncthreads();

    const size_t yrow = ((size_t)(b * N_ + n) * 12 + h) * (size_t)D_;
    #pragma unroll
    for (int k = 0; k < 12; ++k) {
        const float v = sXc[sub][k][t >> 4] * sXs[sub][k][t & 15];
        const unsigned short hv = f2bf(v);
        yhi[yrow + k * 64 + t] = hv;
        ylo[yrow + k * 64 + t] = f2bf(v - bf2f(hv));
    }
}

// ---------------------------------------------------------------------------
extern "C" void kernel_launch(void* const* d_in, const int* in_sizes, int n_in,
                              void* d_out, int out_size, void* d_ws, size_t ws_size,
                              hipStream_t stream) {
    const float* x       = (const float*)d_in[0];
    const float* w_qkv_c = (const float*)d_in[1];
    const float* w_qkv_s = (const float*)d_in[2];
    const float* w_proj  = (const float*)d_in[3];
    const float* b_proj  = (const float*)d_in[4];
    float* out = (float*)d_out;

    unsigned short* xhi = (unsigned short*)d_ws;
    unsigned short* xlo = xhi + (size_t)R_ * KDIM;
    unsigned short* wqkv_hi = xlo + (size_t)R_ * KDIM;
    unsigned short* wqkv_lo = wqkv_hi + (size_t)768 * 768;
    unsigned short* wp_hi   = wqkv_lo + (size_t)768 * 768;
    unsigned short* wp_lo   = wp_hi + (size_t)768 * 768;
    float* qkv = (float*)(wp_lo + (size_t)768 * 768);
    float* xs  = qkv + (size_t)R_ * NQKV_PAD;
    unsigned short* yhi = xhi;   // alias: x splits dead after qkv GEMM
    unsigned short* ylo = xlo;

    convert_split<<<(R_ * KDIM) / 1024, 256, 0, stream>>>(x, xhi, xlo, R_ * KDIM);
    convert_weights<<<(2 * 768 * 768) / 1024, 256, 0, stream>>>(
        w_qkv_c, w_qkv_s, w_proj, wqkv_hi, wqkv_lo, wp_hi, wp_lo);

    {
        const int mtiles = R_ / BM, ntiles = NQKV_PAD / BN;
        gemm_bf16x3<<<mtiles * ntiles, 256, 0, stream>>>(
            xhi, xlo, wqkv_hi, wqkv_lo, nullptr, qkv, R_, NQKV_PAD, KDIM, ntiles);
    }
    spatial_attn_mfma<<<B_ * H_ * C_, 256, 0, stream>>>(qkv, xs);
    chan_attn_combine4<<<(B_ * H_ * N_) / 4, 256, 0, stream>>>(qkv, xs, yhi, ylo);
    {
        const int mtiles = R_ / BM, ntiles = D_ / BN;
        gemm_bf16x3<<<mtiles * ntiles, 256, 0, stream>>>(
            yhi, ylo, wp_hi, wp_lo, b_proj, out, R_, D_, KDIM, ntiles);
    }
}

// Round 9
// 240.558 us; speedup vs baseline: 1.4501x; 1.1045x over previous
//
#include <hip/hip_runtime.h>
#include <math.h>

// Problem constants
#define B_  8
#define N_  196
#define C_  12
#define D_  768
#define H_  12
#define R_  (B_*N_*C_)      // 18816 rows
#define KDIM 768
#define NQKV_PAD 768        // 720 real qkv cols padded to 768

typedef __attribute__((ext_vector_type(8))) short bf16x8;   // 8 bf16 = 4 VGPR
typedef __attribute__((ext_vector_type(4))) float f32x4;

__device__ inline unsigned short f2bf(float f) {
    union { float f; unsigned u; } v; v.f = f;
    unsigned r = v.u + 0x7fffu + ((v.u >> 16) & 1u);   // RNE
    return (unsigned short)(r >> 16);
}
__device__ inline float bf2f(unsigned short h) {
    union { unsigned u; float f; } v; v.u = ((unsigned)h) << 16; return v.f;
}

// ---------------------------------------------------------------------------
// fp32 -> (bf16 hi, bf16 lo) elementwise split. n must be a multiple of 4.
// ---------------------------------------------------------------------------
__global__ __launch_bounds__(256) void convert_split(
    const float* __restrict__ in, unsigned short* __restrict__ hi,
    unsigned short* __restrict__ lo, int n)
{
    int i = (blockIdx.x * 256 + threadIdx.x) * 4;
    if (i >= n) return;
    float4 v = *reinterpret_cast<const float4*>(in + i);
    ushort4 h, l;
    h.x = f2bf(v.x); l.x = f2bf(v.x - bf2f(h.x));
    h.y = f2bf(v.y); l.y = f2bf(v.y - bf2f(h.y));
    h.z = f2bf(v.z); l.z = f2bf(v.z - bf2f(h.z));
    h.w = f2bf(v.w); l.w = f2bf(v.w - bf2f(h.w));
    *reinterpret_cast<ushort4*>(hi + i) = h;
    *reinterpret_cast<ushort4*>(lo + i) = l;
}

// One launch for both weight conversions.
__global__ __launch_bounds__(256) void convert_weights(
    const float* __restrict__ wc, const float* __restrict__ ws,
    const float* __restrict__ wp,
    unsigned short* __restrict__ wqkv_hi, unsigned short* __restrict__ wqkv_lo,
    unsigned short* __restrict__ wp_hi,   unsigned short* __restrict__ wp_lo)
{
    int i = (blockIdx.x * 256 + threadIdx.x) * 4;
    unsigned short* dh; unsigned short* dl; float4 v; int off;
    if (i < 768 * 768) {
        const int r = i / 768, k = i % 768;
        v = make_float4(0.f, 0.f, 0.f, 0.f);
        if (r < 144)      v = *reinterpret_cast<const float4*>(wc + r * 768 + k);
        else if (r < 720) v = *reinterpret_cast<const float4*>(ws + (r - 144) * 768 + k);
        dh = wqkv_hi; dl = wqkv_lo; off = i;
    } else {
        off = i - 768 * 768;
        if (off >= 768 * 768) return;
        v = *reinterpret_cast<const float4*>(wp + off);
        dh = wp_hi; dl = wp_lo;
    }
    ushort4 h, l;
    h.x = f2bf(v.x); l.x = f2bf(v.x - bf2f(h.x));
    h.y = f2bf(v.y); l.y = f2bf(v.y - bf2f(h.y));
    h.z = f2bf(v.z); l.z = f2bf(v.z - bf2f(h.z));
    h.w = f2bf(v.w); l.w = f2bf(v.w - bf2f(h.w));
    *reinterpret_cast<ushort4*>(dh + off) = h;
    *reinterpret_cast<ushort4*>(dl + off) = l;
}

// ---------------------------------------------------------------------------
// bf16x3 split MFMA GEMM (round-7 verified). Unchanged.
// ---------------------------------------------------------------------------
#define BM 128
#define BN 128
#define BK 32

__device__ inline void gload16(const unsigned short* src, void* ldsbase) {
    __builtin_amdgcn_global_load_lds(
        (const __attribute__((address_space(1))) unsigned int*)src,
        (__attribute__((address_space(3))) unsigned int*)ldsbase, 16, 0, 0);
}

__global__ __launch_bounds__(256) void gemm_bf16x3(
    const unsigned short* __restrict__ Ahi, const unsigned short* __restrict__ Alo,
    const unsigned short* __restrict__ Bhi, const unsigned short* __restrict__ Blo,
    const float* __restrict__ bias,
    float* __restrict__ outp, int M, int Nt, int K, int ntiles)
{
    __shared__ unsigned short sAhi[2][BM][BK], sAlo[2][BM][BK];
    __shared__ unsigned short sBhi[2][BN][BK], sBlo[2][BN][BK];

    const int nwg = gridDim.x;
    const int bid = blockIdx.x;
    const int xcd = bid & 7, slot = bid >> 3;
    const int q = nwg >> 3, r = nwg & 7;
    const int wg = (xcd < r ? xcd * (q + 1) : r * (q + 1) + (xcd - r) * q) + slot;
    const int mt = wg / ntiles, nt = wg - mt * ntiles;
    const int m0 = mt * BM, n0 = nt * BN;

    const int tid = threadIdx.x;
    const int w = tid >> 6, l = tid & 63;
    const int wr = (w >> 1) * 64, wc = (w & 1) * 64;

    f32x4 acc[4][4];
    #pragma unroll
    for (int i = 0; i < 4; ++i)
        #pragma unroll
        for (int j = 0; j < 4; ++j)
            acc[i][j] = (f32x4){0.f, 0.f, 0.f, 0.f};

    const int seg0 = w * 1024, seg1 = 4096 + w * 1024;
    const int o0 = seg0 + l * 16, o1 = seg1 + l * 16;
    const int r0 = o0 >> 6, c0 = (o0 & 63) >> 1;
    const int r1 = o1 >> 6, c1 = (o1 & 63) >> 1;

    const int lr = l & 15;
    const int kb = (l >> 4) * 8;

#define STAGE(buf, kk)                                                                     \
    gload16(Ahi + (size_t)(m0 + r0) * K + (kk) + c0, (char*)sAhi + (buf) * 8192 + seg0);   \
    gload16(Ahi + (size_t)(m0 + r1) * K + (kk) + c1, (char*)sAhi + (buf) * 8192 + seg1);   \
    gload16(Alo + (size_t)(m0 + r0) * K + (kk) + c0, (char*)sAlo + (buf) * 8192 + seg0);   \
    gload16(Alo + (size_t)(m0 + r1) * K + (kk) + c1, (char*)sAlo + (buf) * 8192 + seg1);   \
    gload16(Bhi + (size_t)(n0 + r0) * K + (kk) + c0, (char*)sBhi + (buf) * 8192 + seg0);   \
    gload16(Bhi + (size_t)(n0 + r1) * K + (kk) + c1, (char*)sBhi + (buf) * 8192 + seg1);   \
    gload16(Blo + (size_t)(n0 + r0) * K + (kk) + c0, (char*)sBlo + (buf) * 8192 + seg0);   \
    gload16(Blo + (size_t)(n0 + r1) * K + (kk) + c1, (char*)sBlo + (buf) * 8192 + seg1);

    STAGE(0, 0);

    const int KT = K / BK;
    int cur = 0;
    for (int t = 0; t < KT; ++t) {
        if (t + 1 < KT) {
            STAGE(cur ^ 1, (t + 1) * BK);
            asm volatile("s_waitcnt vmcnt(8)" ::: "memory");
        } else {
            asm volatile("s_waitcnt vmcnt(0)" ::: "memory");
        }
        asm volatile("s_barrier" ::: "memory");

        bf16x8 ah[4], al[4];
        #pragma unroll
        for (int fm = 0; fm < 4; ++fm) {
            ah[fm] = *reinterpret_cast<const bf16x8*>(&sAhi[cur][wr + fm * 16 + lr][kb]);
            al[fm] = *reinterpret_cast<const bf16x8*>(&sAlo[cur][wr + fm * 16 + lr][kb]);
        }
        #pragma unroll
        for (int fn = 0; fn < 4; ++fn) {
            bf16x8 bh = *reinterpret_cast<const bf16x8*>(&sBhi[cur][wc + fn * 16 + lr][kb]);
            bf16x8 bl = *reinterpret_cast<const bf16x8*>(&sBlo[cur][wc + fn * 16 + lr][kb]);
            #pragma unroll
            for (int fm = 0; fm < 4; ++fm) {
                acc[fm][fn] = __builtin_amdgcn_mfma_f32_16x16x32_bf16(ah[fm], bh, acc[fm][fn], 0, 0, 0);
                acc[fm][fn] = __builtin_amdgcn_mfma_f32_16x16x32_bf16(ah[fm], bl, acc[fm][fn], 0, 0, 0);
                acc[fm][fn] = __builtin_amdgcn_mfma_f32_16x16x32_bf16(al[fm], bh, acc[fm][fn], 0, 0, 0);
            }
        }
        asm volatile("s_barrier" ::: "memory");
        cur ^= 1;
    }
#undef STAGE

    const int rg = (l >> 4) * 4;
    #pragma unroll
    for (int fm = 0; fm < 4; ++fm) {
        #pragma unroll
        for (int fn = 0; fn < 4; ++fn) {
            const int row = m0 + wr + fm * 16 + rg;
            const int col = n0 + wc + fn * 16 + lr;
            const float bv = bias ? bias[col] : 0.f;
            #pragma unroll
            for (int rr = 0; rr < 4; ++rr)
                outp[(size_t)(row + rr) * Nt + col] = acc[fm][fn][rr] + bv;
        }
    }
}

// ---------------------------------------------------------------------------
// MFMA spatial attention, SIMPLIFIED SOFTMAX:
//  - no max-subtraction (scores |s| <~ 2 by construction; exp(s) fp32-safe)
//  - P and V in bf16-hi only for PV (1 MFMA/chunk instead of 3)
//  - lsum reduced per-lane, 2 shfl once at the end
//  - pad k-rows masked via s=-1e30 -> expf -> 0 (unchanged mechanism)
// ---------------------------------------------------------------------------
__global__ __launch_bounds__(256) void spatial_attn_mfma(
    const float* __restrict__ qkv,
    float* __restrict__ xs_out)
{
    __shared__ unsigned short Kl[224][40];     // cols: Khi(0..15) Klo(16..31) pad
    __shared__ unsigned short Ql[208][40];     // cols: Qhi(0..15) Qlo(16..31) pad
    __shared__ unsigned short VtH[16][232];    // V^T hi: [d][k]
    __shared__ unsigned short Pb[4][16][40];   // per-wave: [q][Phi(32)|pad]

    const int bid = blockIdx.x;                // 1152 = 8*12*12
    const int c = bid % 12;
    const int h = (bid / 12) % 12;
    const int b = bid / 144;
    const int tid = threadIdx.x;
    const int w = tid >> 6, l = tid & 63;
    const int fl = l & 15, g = l >> 4;

    for (int idx = tid; idx < N_ * 16; idx += 256) {
        const int n = idx >> 4, e = idx & 15;
        const float* base = qkv + (size_t)((b * N_ + n) * 12 + c) * NQKV_PAD + 144 + h * 16 + e;
        const float qv = base[0] * 0.25f;
        const float kv = base[192];
        const float vv = base[384];
        const unsigned short qh = f2bf(qv), kh = f2bf(kv);
        Ql[n][e]      = qh;  Ql[n][16 + e] = f2bf(qv - bf2f(qh));
        Kl[n][e]      = kh;  Kl[n][16 + e] = f2bf(kv - bf2f(kh));
        VtH[e][n]     = f2bf(vv);
    }
    for (int idx = tid; idx < 16 * 28; idx += 256) {
        const int d = idx / 28, n = 196 + idx % 28;
        VtH[d][n] = 0;
    }
    __syncthreads();

    f32x4 accO[4];
    float lsum[4];
    #pragma unroll
    for (int j = 0; j < 4; ++j) {
        accO[j] = (f32x4){0.f, 0.f, 0.f, 0.f};
        lsum[j] = 0.f;
    }
    const f32x4 zf = (f32x4){0.f, 0.f, 0.f, 0.f};
    const bf16x8 zb = (bf16x8){0, 0, 0, 0, 0, 0, 0, 0};

    for (int ch = 0; ch < 7; ++ch) {
        const int kb0 = ch * 32;
        const bf16x8 A1a = *reinterpret_cast<const bf16x8*>(&Kl[kb0 + fl][8 * g]);
        const bf16x8 A1b = *reinterpret_cast<const bf16x8*>(&Kl[kb0 + 16 + fl][8 * g]);
        const bf16x8 A2a = *reinterpret_cast<const bf16x8*>(&Kl[kb0 + fl][8 * (g & 1)]);
        const bf16x8 A2b = *reinterpret_cast<const bf16x8*>(&Kl[kb0 + 16 + fl][8 * (g & 1)]);
        const bf16x8 AvH = *reinterpret_cast<const bf16x8*>(&VtH[fl][kb0 + 8 * g]);

        #pragma unroll
        for (int j = 0; j < 4; ++j) {
            const int qt = w + 4 * j;
            if (qt > 12) continue;
            const int qrow = qt * 16 + fl;
            const bf16x8 Bq1 = *reinterpret_cast<const bf16x8*>(&Ql[qrow][8 * (g & 1)]);
            bf16x8 Bq2 = *reinterpret_cast<const bf16x8*>(&Ql[qrow][16 + 8 * (g & 1)]);
            if (g >= 2) Bq2 = zb;

            f32x4 T0 = zf, T1 = zf;
            T0 = __builtin_amdgcn_mfma_f32_16x16x32_bf16(A1a, Bq1, T0, 0, 0, 0);
            T0 = __builtin_amdgcn_mfma_f32_16x16x32_bf16(A2a, Bq2, T0, 0, 0, 0);
            T1 = __builtin_amdgcn_mfma_f32_16x16x32_bf16(A1b, Bq1, T1, 0, 0, 0);
            T1 = __builtin_amdgcn_mfma_f32_16x16x32_bf16(A2b, Bq2, T1, 0, 0, 0);

            float s0 = T0[0], s1 = T0[1], s2 = T0[2], s3 = T0[3];
            float s4 = T1[0], s5 = T1[1], s6 = T1[2], s7 = T1[3];
            if (ch == 6) {                      // mask pad k-rows (expf(-1e30)=0)
                const int kg = kb0 + 4 * g;
                if (kg + 0 >= 196) s0 = -1e30f;
                if (kg + 1 >= 196) s1 = -1e30f;
                if (kg + 2 >= 196) s2 = -1e30f;
                if (kg + 3 >= 196) s3 = -1e30f;
                s4 = -1e30f; s5 = -1e30f; s6 = -1e30f; s7 = -1e30f;
            }
            const float p0 = __expf(s0), p1 = __expf(s1);
            const float p2 = __expf(s2), p3 = __expf(s3);
            const float p4 = __expf(s4), p5 = __expf(s5);
            const float p6 = __expf(s6), p7 = __expf(s7);
            lsum[j] += ((p0 + p1) + (p2 + p3)) + ((p4 + p5) + (p6 + p7));

            uint2 whi0, whi1;
            whi0.x = (unsigned)f2bf(p0) | ((unsigned)f2bf(p1) << 16);
            whi0.y = (unsigned)f2bf(p2) | ((unsigned)f2bf(p3) << 16);
            whi1.x = (unsigned)f2bf(p4) | ((unsigned)f2bf(p5) << 16);
            whi1.y = (unsigned)f2bf(p6) | ((unsigned)f2bf(p7) << 16);
            *reinterpret_cast<uint2*>(&Pb[w][fl][4 * g])      = whi0;   // krows 4g..
            *reinterpret_cast<uint2*>(&Pb[w][fl][16 + 4 * g]) = whi1;   // krows 16+4g..

            const bf16x8 BpH = *reinterpret_cast<const bf16x8*>(&Pb[w][fl][8 * g]);
            accO[j] = __builtin_amdgcn_mfma_f32_16x16x32_bf16(AvH, BpH, accO[j], 0, 0, 0);
        }
    }

    // final: reduce lsum across the 4 k-groups (same fl), normalize, store
    #pragma unroll
    for (int j = 0; j < 4; ++j) {
        const int qt = w + 4 * j;
        if (qt > 12) continue;
        float ls = lsum[j];
        ls += __shfl_xor(ls, 16);
        ls += __shfl_xor(ls, 32);
        const int n = qt * 16 + fl;
        if (n < 196) {
            const float inv = 1.f / ls;
            float4 o;
            o.x = accO[j][0] * inv; o.y = accO[j][1] * inv;
            o.z = accO[j][2] * inv; o.w = accO[j][3] * inv;
            const size_t base = ((size_t)((b * 12 + h) * N_ + n) * 12 + c) * 16 + 4 * g;
            *reinterpret_cast<float4*>(&xs_out[base]) = o;
        }
    }
}

// ---------------------------------------------------------------------------
// Channel attention + outer-product combine, 4 rows per 256-thread block.
// ---------------------------------------------------------------------------
__global__ __launch_bounds__(256) void chan_attn_combine4(
    const float* __restrict__ qkv,
    const float* __restrict__ xs,
    unsigned short* __restrict__ yhi,
    unsigned short* __restrict__ ylo)
{
    const int sub = threadIdx.x >> 6;
    const int t = threadIdx.x & 63;
    const int flat = blockIdx.x * 4 + sub;     // (b*12+h)*196 + n
    const int n = flat % 196;
    const int h = (flat / 196) % 12;
    const int b = flat / 2352;

    __shared__ float sQ[4][12][4], sK[4][12][4], sV[4][12][4], sXc[4][12][4];
    __shared__ float sXs[4][12][16];

    for (int idx = t; idx < 144; idx += 64) {
        const int c = idx / 12, rem = idx % 12, s = rem >> 2, e = rem & 3;
        const float v = qkv[(size_t)((b * N_ + n) * 12 + c) * NQKV_PAD + s * 48 + h * 4 + e];
        if (s == 0) sQ[sub][c][e] = v;
        else if (s == 1) sK[sub][c][e] = v;
        else sV[sub][c][e] = v;
    }
    for (int idx = t; idx < 192; idx += 64) {
        const int c = idx >> 4, j = idx & 15;
        sXs[sub][c][j] = xs[((size_t)flat * 12 + c) * 16 + j];
    }
    __syncthreads();

    if (t < 12) {
        const int c = t;
        float s[12];
        float m = -INFINITY;
        #pragma unroll
        for (int c2 = 0; c2 < 12; ++c2) {
            float d = 0.f;
            #pragma unroll
            for (int e = 0; e < 4; ++e) d += sQ[sub][c][e] * sK[sub][c2][e];
            s[c2] = d * 0.5f;
            m = fmaxf(m, s[c2]);
        }
        float lsum = 0.f;
        #pragma unroll
        for (int c2 = 0; c2 < 12; ++c2) { s[c2] = __expf(s[c2] - m); lsum += s[c2]; }
        const float inv = 1.f / lsum;
        #pragma unroll
        for (int i = 0; i < 4; ++i) {
            float a = 0.f;
            #pragma unroll
            for (int c2 = 0; c2 < 12; ++c2) a += s[c2] * sV[sub][c2][i];
            sXc[sub][c][i] = a * inv;
        }
    }
    __syncthreads();

    const size_t yrow = ((size_t)(b * N_ + n) * 12 + h) * (size_t)D_;
    #pragma unroll
    for (int k = 0; k < 12; ++k) {
        const float v = sXc[sub][k][t >> 4] * sXs[sub][k][t & 15];
        const unsigned short hv = f2bf(v);
        yhi[yrow + k * 64 + t] = hv;
        ylo[yrow + k * 64 + t] = f2bf(v - bf2f(hv));
    }
}

// ---------------------------------------------------------------------------
extern "C" void kernel_launch(void* const* d_in, const int* in_sizes, int n_in,
                              void* d_out, int out_size, void* d_ws, size_t ws_size,
                              hipStream_t stream) {
    const float* x       = (const float*)d_in[0];
    const float* w_qkv_c = (const float*)d_in[1];
    const float* w_qkv_s = (const float*)d_in[2];
    const float* w_proj  = (const float*)d_in[3];
    const float* b_proj  = (const float*)d_in[4];
    float* out = (float*)d_out;

    unsigned short* xhi = (unsigned short*)d_ws;
    unsigned short* xlo = xhi + (size_t)R_ * KDIM;
    unsigned short* wqkv_hi = xlo + (size_t)R_ * KDIM;
    unsigned short* wqkv_lo = wqkv_hi + (size_t)768 * 768;
    unsigned short* wp_hi   = wqkv_lo + (size_t)768 * 768;
    unsigned short* wp_lo   = wp_hi + (size_t)768 * 768;
    float* qkv = (float*)(wp_lo + (size_t)768 * 768);
    float* xs  = qkv + (size_t)R_ * NQKV_PAD;
    unsigned short* yhi = xhi;   // alias: x splits dead after qkv GEMM
    unsigned short* ylo = xlo;

    convert_split<<<(R_ * KDIM) / 1024, 256, 0, stream>>>(x, xhi, xlo, R_ * KDIM);
    convert_weights<<<(2 * 768 * 768) / 1024, 256, 0, stream>>>(
        w_qkv_c, w_qkv_s, w_proj, wqkv_hi, wqkv_lo, wp_hi, wp_lo);

    {
        const int mtiles = R_ / BM, ntiles = NQKV_PAD / BN;
        gemm_bf16x3<<<mtiles * ntiles, 256, 0, stream>>>(
            xhi, xlo, wqkv_hi, wqkv_lo, nullptr, qkv, R_, NQKV_PAD, KDIM, ntiles);
    }
    spatial_attn_mfma<<<B_ * H_ * C_, 256, 0, stream>>>(qkv, xs);
    chan_attn_combine4<<<(B_ * H_ * N_) / 4, 256, 0, stream>>>(qkv, xs, yhi, ylo);
    {
        const int mtiles = R_ / BM, ntiles = D_ / BN;
        gemm_bf16x3<<<mtiles * ntiles, 256, 0, stream>>>(
            yhi, ylo, wp_hi, wp_lo, b_proj, out, R_, D_, KDIM, ntiles);
    }
}